// Round 2
// baseline (637.318 us; speedup 1.0000x reference)
//
#include <hip/hip_runtime.h>
#include <hip/hip_bf16.h>

// ---- problem constants ----
#define B_SZ   2
#define L_SZ   2048
#define DM     2048
#define DS     128
#define DCV    4
#define HD     64
#define CH     256
#define DI     4096
#define NH     64
#define DIP    8512
#define CDIM   4352
#define NP     8576      // DIP padded to 67*128 (zx row stride)
#define NP2    8704      // GEMM N padded to 34*256 (wtb rows only)
#define MROWS  4096      // B_SZ*L_SZ
#define NCK    8         // L_SZ/CH

typedef __attribute__((ext_vector_type(8))) short bf16x8;
typedef __attribute__((ext_vector_type(4))) float f32x4;
typedef unsigned short u16;

__device__ __forceinline__ u16 f2bf(float f) {
    union { float f; unsigned u; } c; c.f = f;
    unsigned r = c.u + 0x7fffu + ((c.u >> 16) & 1u);
    return (u16)(r >> 16);
}
__device__ __forceinline__ float bf2f(u16 b) {
    union { unsigned u; float f; } c; c.u = ((unsigned)b) << 16; return c.f;
}

// async global->LDS copy, 16 B per lane (global_load_lds_dwordx4)
__device__ __forceinline__ void async16(const u16* g, u16* l) {
    __builtin_amdgcn_global_load_lds(
        (const __attribute__((address_space(1))) unsigned int*)(g),
        (__attribute__((address_space(3))) unsigned int*)(l),
        16, 0, 0);
}

// ---- 0a: u f32 -> bf16 ----
__global__ void cvt_u_kernel(const float* __restrict__ u, u16* __restrict__ ub) {
    int i = blockIdx.x * 256 + threadIdx.x;
    float4 v = ((const float4*)u)[i];
    ushort4 o;
    o.x = f2bf(v.x); o.y = f2bf(v.y); o.z = f2bf(v.z); o.w = f2bf(v.w);
    ((ushort4*)ub)[i] = o;
}

// ---- 0b: w_in (K=2048 x DIP) f32 -> w_inT (NP2 x K) bf16, zero-pad rows >= DIP ----
__global__ void transpose_w_kernel(const float* __restrict__ w, u16* __restrict__ wt) {
    __shared__ float tile[32][33];
    int n0 = blockIdx.x * 32, k0 = blockIdx.y * 32;
    int tx = threadIdx.x & 31, ty = threadIdx.x >> 5;
    for (int j = 0; j < 32; j += 8) {
        int k = k0 + ty + j, n = n0 + tx;
        tile[ty + j][tx] = (n < DIP) ? w[(size_t)k * DIP + n] : 0.f;
    }
    __syncthreads();
    for (int j = 0; j < 32; j += 8) {
        int n = n0 + ty + j, k = k0 + tx;
        wt[(size_t)n * DM + k] = f2bf(tile[tx][ty + j]);
    }
}

// ---- 1: GEMM zxbcdt = u @ w_in -> bf16 [MROWS][NP] ----
// 256x256 tile, BK=32, 8 waves (2Mx4N, 128x64 each => 0.375 ds_reads/MFMA),
// TRIPLE-buffered LDS (96KB) so per-K-tile wait is counted vmcnt(4) (never drains),
// 2 phases/K-tile, XOR-swizzled LDS, setprio around MFMA, XCD swizzle.
#define G_NKT   64        // 2048/32 K-tiles
#define G_NBLK  544       // 16 * 34
__global__ __launch_bounds__(512) void gemm_kernel(const u16* __restrict__ A,
                                                   const u16* __restrict__ Bt,
                                                   u16* __restrict__ C) {
    __shared__ u16 As[3][256 * 32];   // 48 KB
    __shared__ u16 Bs[3][256 * 32];   // 48 KB

    int bid = blockIdx.x;
    int bidx = (bid & 7) * (G_NBLK / 8) + (bid >> 3);   // XCD swizzle (544 % 8 == 0)
    const int width = 8 * 34;                           // GM * N-tiles
    int group = bidx / width;
    int rem = bidx - group * width;
    int pid_m = group * 8 + (rem & 7);
    int pid_n = rem >> 3;
    const int m0 = pid_m * 256, n0 = pid_n * 256;

    const int tid = threadIdx.x;
    const int lane = tid & 63;
    const int wid = tid >> 6;
    const int wm = (wid >> 2) * 128;  // 0,128
    const int wn = (wid & 3) * 64;    // 0,64,128,192
    const int quad = lane >> 4, lm = lane & 15;

    // staging geometry: 512 threads cover 128 rows x 32 cols (8 KB) per issue
    const int srow = tid >> 2;                 // 0..127
    const int c4 = tid & 3;
    const int scol = (c4 ^ (srow & 3)) * 8;    // pre-swizzled source col chunk (u16)
    const u16* aS = A  + (size_t)(m0 + srow) * DM + scol;
    const u16* bS = Bt + (size_t)(n0 + srow) * DM + scol;
    const int ldo = srow * 32 + c4 * 8;        // linear LDS dest (= tid*16B)

    f32x4 acc[8][4] = {};

    // ---- prologue: tile0 -> buf0, tile1 -> buf1 (4 issues each) ----
    for (int t = 0; t < 2; t++) {
        const u16* as = aS + t * 32;
        const u16* bs = bS + t * 32;
        async16(as,                    &As[t][ldo]);
        async16(as + (size_t)128 * DM, &As[t][ldo + 4096]);
        async16(bs,                    &Bs[t][ldo]);
        async16(bs + (size_t)128 * DM, &Bs[t][ldo + 4096]);
    }
    asm volatile("s_waitcnt vmcnt(4)" ::: "memory");    // tile0 landed, tile1 in flight
    __builtin_amdgcn_s_barrier();

    for (int kt = 0; kt < G_NKT; kt++) {
        unsigned cur = (unsigned)kt % 3u;
        unsigned sb  = (unsigned)(kt + 2) % 3u;
        const bool dost = (kt + 2) < G_NKT;
        const u16* ab = &As[cur][0];
        const u16* bb = &Bs[cur][0];
        const u16* as = aS + (kt + 2) * 32;
        const u16* bs = bS + (kt + 2) * 32;

        // ---- phase 0: A-frags i0-3 + all B-frags ; stage A(t+2) ; 16 MFMA ----
        bf16x8 af[4], bfr[4];
        for (int i = 0; i < 4; i++) {
            int row = wm + i * 16 + lm;
            af[i] = *(const bf16x8*)(ab + row * 32 + ((quad ^ (row & 3)) * 8));
        }
        for (int j = 0; j < 4; j++) {
            int row = wn + j * 16 + lm;
            bfr[j] = *(const bf16x8*)(bb + row * 32 + ((quad ^ (row & 3)) * 8));
        }
        if (dost) {
            async16(as,                    &As[sb][ldo]);
            async16(as + (size_t)128 * DM, &As[sb][ldo + 4096]);
        }
        __builtin_amdgcn_s_barrier();
        asm volatile("s_waitcnt lgkmcnt(0)" ::: "memory");
        __builtin_amdgcn_s_setprio(1);
        for (int i = 0; i < 4; i++)
            for (int j = 0; j < 4; j++)
                acc[i][j] = __builtin_amdgcn_mfma_f32_16x16x32_bf16(af[i], bfr[j], acc[i][j], 0, 0, 0);
        __builtin_amdgcn_s_setprio(0);
        __builtin_amdgcn_s_barrier();

        // ---- phase 1: A-frags i4-7 ; stage B(t+2) ; counted vmcnt ; 16 MFMA (B reused) ----
        bf16x8 ag[4];
        for (int i = 0; i < 4; i++) {
            int row = wm + 64 + i * 16 + lm;
            ag[i] = *(const bf16x8*)(ab + row * 32 + ((quad ^ (row & 3)) * 8));
        }
        if (dost) {
            async16(bs,                    &Bs[sb][ldo]);
            async16(bs + (size_t)128 * DM, &Bs[sb][ldo + 4096]);
        }
        if (kt < G_NKT - 2) { asm volatile("s_waitcnt vmcnt(4)" ::: "memory"); }
        else                { asm volatile("s_waitcnt vmcnt(0)" ::: "memory"); }
        __builtin_amdgcn_s_barrier();
        asm volatile("s_waitcnt lgkmcnt(0)" ::: "memory");
        __builtin_amdgcn_s_setprio(1);
        for (int i = 0; i < 4; i++)
            for (int j = 0; j < 4; j++)
                acc[i + 4][j] = __builtin_amdgcn_mfma_f32_16x16x32_bf16(ag[i], bfr[j], acc[i + 4][j], 0, 0, 0);
        __builtin_amdgcn_s_setprio(0);
        __builtin_amdgcn_s_barrier();
    }

    for (int i = 0; i < 8; i++)
        for (int j = 0; j < 4; j++)
            for (int r = 0; r < 4; r++) {
                int gm = m0 + wm + i * 16 + quad * 4 + r;
                int gn = n0 + wn + j * 16 + lm;
                if (gn < NP)
                    C[(size_t)gm * NP + gn] = f2bf(acc[i][j][r]);
            }
}

// ---- 2: causal depthwise conv(4) + SiLU — vectorized, 8 channels/thread ----
__global__ void conv_silu_kernel(const u16* __restrict__ zx, const float* __restrict__ cw,
                                 const float* __restrict__ cb, u16* __restrict__ xbc) {
    int tid = threadIdx.x;
    int c8  = blockIdx.x * 32 + (tid & 31);        // 0..543
    int row = blockIdx.y * 16 + (tid >> 5);        // 0..4095
    int c0  = c8 * 8;
    int l = row & (L_SZ - 1);

    float w_[8][4];
    {
        const float4* wp = (const float4*)(cw + (size_t)c0 * 4);
        for (int e = 0; e < 8; e++) {
            float4 v = wp[e];
            w_[e][0] = v.x; w_[e][1] = v.y; w_[e][2] = v.z; w_[e][3] = v.w;
        }
    }
    float acc[8];
    {
        float4 b0 = *(const float4*)(cb + c0);
        float4 b1 = *(const float4*)(cb + c0 + 4);
        acc[0] = b0.x; acc[1] = b0.y; acc[2] = b0.z; acc[3] = b0.w;
        acc[4] = b1.x; acc[5] = b1.y; acc[6] = b1.z; acc[7] = b1.w;
    }
    for (int k = 0; k < DCV; k++) {
        int ls = l - 3 + k;
        if (ls >= 0) {
            bf16x8 v = *(const bf16x8*)(zx + (size_t)(row - 3 + k) * NP + DI + c0);
            for (int e = 0; e < 8; e++)
                acc[e] += bf2f((u16)v[e]) * w_[e][k];
        }
    }
    bf16x8 o;
    for (int e = 0; e < 8; e++) {
        float s = acc[e] / (1.f + expf(-acc[e]));
        o[e] = (short)f2bf(s);
    }
    *(bf16x8*)(xbc + (size_t)row * CDIM + c0) = o;
}

// ---- 3: dt = softplus(raw+bias) -> dtbT[h][row]; per-chunk cumsum of dA -> acs ----
__global__ void dt_scan_kernel(const u16* __restrict__ zx, const float* __restrict__ dt_bias,
                               const float* __restrict__ A_log, float* __restrict__ dtbT,
                               float* __restrict__ acs) {
    int bid = blockIdx.x;
    int h = bid & 63, c = (bid >> 6) & 7, b = bid >> 9;
    int t = threadIdx.x;
    int row = b * L_SZ + c * CH + t;
    float raw = bf2f(zx[(size_t)row * NP + (DI + CDIM) + h]) + dt_bias[h];
    float dtv = (raw > 20.f) ? raw : log1pf(expf(raw));
    float dA = dtv * (-expf(A_log[h]));
    dtbT[(size_t)h * MROWS + row] = dtv;
    __shared__ float sc[256];
    sc[t] = dA;
    for (int off = 1; off < 256; off <<= 1) {
        __syncthreads();
        float v = (t >= off) ? sc[t - off] : 0.f;
        __syncthreads();
        sc[t] += v;
    }
    acs[((size_t)((b * NH + h) * NCK + c)) * CH + t] = sc[t];
}

// ---- 4: Gb[t][s] = masked bf16( sum_n Cm[t,n]*Bm[s,n] ) per (b,c) ----
__global__ void g_kernel(const u16* __restrict__ xbc, u16* __restrict__ Gb) {
    int blk = blockIdx.x;
    int bc = blk >> 4;
    int tile = blk & 15;
    int tb0 = (tile >> 2) * 64, sb0 = (tile & 3) * 64;
    int row0 = bc * CH;
    __shared__ float Ct[64][65], Bt_[64][65];
    int tq = (threadIdx.x >> 4) * 4;
    int sq = (threadIdx.x & 15) * 4;
    float acc[4][4] = {};
    for (int nh = 0; nh < 2; nh++) {
        __syncthreads();
        int r = threadIdx.x >> 2, cc = (threadIdx.x & 3) * 16;
        for (int q = 0; q < 16; q += 4) {
            ushort4 cv = *(const ushort4*)&xbc[(size_t)(row0 + tb0 + r) * CDIM + (DI + DS) + nh * 64 + cc + q];
            ushort4 bv = *(const ushort4*)&xbc[(size_t)(row0 + sb0 + r) * CDIM + DI + nh * 64 + cc + q];
            Ct[r][cc + q] = bf2f(cv.x); Ct[r][cc + q + 1] = bf2f(cv.y); Ct[r][cc + q + 2] = bf2f(cv.z); Ct[r][cc + q + 3] = bf2f(cv.w);
            Bt_[r][cc + q] = bf2f(bv.x); Bt_[r][cc + q + 1] = bf2f(bv.y); Bt_[r][cc + q + 2] = bf2f(bv.z); Bt_[r][cc + q + 3] = bf2f(bv.w);
        }
        __syncthreads();
        for (int n = 0; n < 64; n++) {
            float a[4], bb[4];
            for (int i = 0; i < 4; i++) a[i] = Ct[tq + i][n];
            for (int j = 0; j < 4; j++) bb[j] = Bt_[sq + j][n];
            for (int i = 0; i < 4; i++)
                for (int j = 0; j < 4; j++) acc[i][j] += a[i] * bb[j];
        }
    }
    for (int i = 0; i < 4; i++)
        for (int j = 0; j < 4; j++) {
            int t = tb0 + tq + i, s = sb0 + sq + j;
            Gb[((size_t)(bc * CH + t)) * CH + s] = (s <= t) ? f2bf(acc[i][j]) : (u16)0;
        }
}

// ---- 4b: BmT[n][row] = xbc[row][DI+n]  (128 x 4096 bf16) ----
__global__ void bmt_kernel(const u16* __restrict__ xbc, u16* __restrict__ BmT) {
    __shared__ u16 tile[64 * 72];
    int n0 = blockIdx.x * 64, r0 = blockIdx.y * 64;
    int tid = threadIdx.x;
    {
        int r = tid >> 2, seg = (tid & 3) * 16;
        const u16* src = xbc + (size_t)(r0 + r) * CDIM + DI + n0 + seg;
        *(int4*)(tile + r * 72 + seg)     = *(const int4*)(src);
        *(int4*)(tile + r * 72 + seg + 8) = *(const int4*)(src + 8);
    }
    __syncthreads();
    {
        int n = tid >> 2, seg = (tid & 3) * 16;
        union { u16 v[16]; int4 q[2]; } o;
        for (int q = 0; q < 16; q++) o.v[q] = tile[(seg + q) * 72 + n];
        u16* dst = BmT + (size_t)(n0 + n) * MROWS + r0 + seg;
        *(int4*)(dst)     = o.q[0];
        *(int4*)(dst + 8) = o.q[1];
    }
}

// ---- 5: states[p][n] = sum_t (X[t,p]*dt[t]*decay[t]) * Bm[t,n]  per (b,c,h) — MFMA ----
__global__ __launch_bounds__(256) void states_kernel(const u16* __restrict__ xbc, const u16* __restrict__ BmT,
                                                     const float* __restrict__ dtbT, const float* __restrict__ acs_g,
                                                     float* __restrict__ states) {
    int bid = blockIdx.x;                 // (b,c,h)
    int h = bid & 63, c = (bid >> 6) & 7, b = bid >> 9;
    int row0 = b * L_SZ + c * CH;
    int tid = threadIdx.x;
    int lane = tid & 63, w = tid >> 6;
    int quad = lane >> 4, lm = lane & 15;
    int mh = (w >> 1) * 32, nh = (w & 1) * 64;

    __shared__ float wsc[CH];
    __shared__ u16 XTs[64 * 136];         // [p][t_local], pad 136

    {
        size_t abase = ((size_t)((b * NH + h) * NCK + c)) * CH;
        float a255 = acs_g[abase + 255];
        float at = acs_g[abase + tid];
        wsc[tid] = dtbT[(size_t)h * MROWS + row0 + tid] * expf(a255 - at);
    }
    f32x4 acc[2][4] = {};
    for (int k0 = 0; k0 < CH; k0 += 128) {
        __syncthreads();
        {   // stage scaled-transposed X chunk: thread -> (t row, 32 p)
            int tl = tid >> 1;            // 0..127
            int pseg = (tid & 1) * 32;
            float wv = wsc[k0 + tl];
            const u16* xr = xbc + (size_t)(row0 + k0 + tl) * CDIM + h * HD + pseg;
            for (int q4 = 0; q4 < 4; q4++) {
                bf16x8 v = *(const bf16x8*)(xr + q4 * 8);
                for (int e = 0; e < 8; e++)
                    XTs[(pseg + q4 * 8 + e) * 136 + tl] = f2bf(bf2f((u16)v[e]) * wv);
            }
        }
        __syncthreads();
        for (int ks = 0; ks < 4; ks++) {
            bf16x8 af[2];
            for (int i = 0; i < 2; i++)
                af[i] = *(const bf16x8*)(XTs + (mh + i * 16 + lm) * 136 + ks * 32 + quad * 8);
            for (int j = 0; j < 4; j++) {
                const u16* brow = BmT + (size_t)(nh + j * 16 + lm) * MROWS + row0 + k0 + ks * 32 + quad * 8;
                bf16x8 bfr = *(const bf16x8*)brow;
                for (int i = 0; i < 2; i++)
                    acc[i][j] = __builtin_amdgcn_mfma_f32_16x16x32_bf16(af[i], bfr, acc[i][j], 0, 0, 0);
            }
        }
    }
    float* st = states + (size_t)bid * (HD * DS);
    for (int i = 0; i < 2; i++)
        for (int j = 0; j < 4; j++)
            for (int r = 0; r < 4; r++) {
                int p = mh + i * 16 + quad * 4 + r;
                int n = nh + j * 16 + lm;
                st[p * DS + n] = acc[i][j][r];
            }
}

// ---- 6: inter-chunk scan IN PLACE ----
__global__ void cscan_kernel(float* __restrict__ states, const float* __restrict__ acs_g) {
    int bid = blockIdx.x;
    int h = bid & 63, b = bid >> 6;
    int tid = threadIdx.x;
    float4 carry[8];
    for (int i = 0; i < 8; i++) carry[i] = make_float4(0.f, 0.f, 0.f, 0.f);
    for (int c = 0; c < NCK; c++) {
        size_t base = ((size_t)((b * NCK + c) * NH + h)) * (HD * DS);
        float g = expf(acs_g[((size_t)((b * NH + h) * NCK + c)) * CH + (CH - 1)]);
        float4* sp = (float4*)(states + base);
        for (int i = 0; i < 8; i++) {
            int idx = tid + 256 * i;
            float4 s = sp[idx];
            sp[idx] = carry[i];
            carry[i].x = carry[i].x * g + s.x;
            carry[i].y = carry[i].y * g + s.y;
            carry[i].z = carry[i].z * g + s.z;
            carry[i].w = carry[i].w * g + s.w;
        }
    }
}

// ---- 7: y = Yo + Yd + D_skip*x per (b,c,h) — MFMA, register-built Yd A-frags ----
__global__ __launch_bounds__(256) void y_kernel(const u16* __restrict__ xbc, const float* __restrict__ dtbT,
                                                const float* __restrict__ acs_g, const u16* __restrict__ Gb,
                                                const float* __restrict__ init_st, const float* __restrict__ D_skip,
                                                u16* __restrict__ y) {
    int bid = blockIdx.x;                 // (b,c,h)
    int h = bid & 63, c = (bid >> 6) & 7, b = bid >> 9;
    int bc = b * NCK + c;
    int row0 = b * L_SZ + c * CH;
    int tid = threadIdx.x;
    int lane = tid & 63, w = tid >> 6;
    int wt = w * 64;
    int quad = lane >> 4, lm = lane & 15;

    __shared__ float acs[CH];             // 1 KB
    __shared__ u16 Ssb[64 * 136];         // 17.4 KB  states bf16 [p][n] pad 136
    __shared__ u16 XT[64 * 72];           // 9.2 KB   Xdt^T [p][s_local] pad 72

    acs[tid] = acs_g[((size_t)((b * NH + h) * NCK + c)) * CH + tid];
    {   // init_st f32 [p][n] -> bf16 LDS padded
        const float4* sg = (const float4*)(init_st + ((size_t)(bc * NH + h)) * (HD * DS));
        for (int i = 0; i < 8; i++) {
            int g = tid + 256 * i;
            int p = g >> 5, n4 = (g & 31) * 4;
            float4 v = sg[g];
            ushort4 o;
            o.x = f2bf(v.x); o.y = f2bf(v.y); o.z = f2bf(v.z); o.w = f2bf(v.w);
            *(ushort4*)(Ssb + p * 136 + n4) = o;
        }
    }
    __syncthreads();

    f32x4 acc[4][4] = {};
    // ---- Yo: A = raw Cm rows from global; B = Ssb ----
    for (int i = 0; i < 4; i++) {
        const u16* arow = xbc + (size_t)(row0 + wt + i * 16 + lm) * CDIM + (DI + DS);
        for (int ks = 0; ks < 4; ks++) {
            bf16x8 af = *(const bf16x8*)(arow + ks * 32 + quad * 8);
            for (int j = 0; j < 4; j++) {
                bf16x8 bfr = *(const bf16x8*)(Ssb + (j * 16 + lm) * 136 + ks * 32 + quad * 8);
                acc[i][j] = __builtin_amdgcn_mfma_f32_16x16x32_bf16(af, bfr, acc[i][j], 0, 0, 0);
            }
        }
    }
    for (int i = 0; i < 4; i++) {
        float et[4];
        for (int r = 0; r < 4; r++) et[r] = expf(acs[wt + i * 16 + quad * 4 + r]);
        for (int j = 0; j < 4; j++)
            for (int r = 0; r < 4; r++) acc[i][j][r] *= et[r];
    }

    // ---- Yd: A-frag built in registers from masked Gb + exp; B = XT (dt folded) ----
    const u16* gball = Gb + (size_t)bc * CH * CH;
    for (int s0 = 0; s0 < CH; s0 += 64) {
        __syncthreads();
        {   // XT[p][s_local] = x[s][p] * dt[s]
            int r = tid >> 2, cseg = (tid & 3) * 16;
            int row = row0 + s0 + r;
            float dv = dtbT[(size_t)h * MROWS + row];
            const u16* xr = xbc + (size_t)row * CDIM + h * HD + cseg;
            for (int q8 = 0; q8 < 2; q8++) {
                bf16x8 v = *(const bf16x8*)(xr + q8 * 8);
                for (int e = 0; e < 8; e++)
                    XT[(cseg + q8 * 8 + e) * 72 + r] = f2bf(bf2f((u16)v[e]) * dv);
            }
        }
        __syncthreads();
        if (wt + 63 < s0) continue;
        for (int i = 0; i < 4; i++) {
            int tTop = wt + i * 16 + 15;
            if (tTop < s0) continue;
            int t = wt + i * 16 + lm;
            float at = acs[t];
            const u16* grow_ = gball + (size_t)t * CH + s0;
            for (int ks = 0; ks < 2; ks++) {
                if (s0 + ks * 32 > tTop) continue;
                bf16x8 g8 = *(const bf16x8*)(grow_ + ks * 32 + quad * 8);
                const float* asp = &acs[s0 + ks * 32 + quad * 8];
                bf16x8 af;
                for (int e = 0; e < 8; e++) {
                    float m = bf2f((u16)g8[e]) * expf(fminf(at - asp[e], 0.f));
                    af[e] = (short)f2bf(m);
                }
                for (int j = 0; j < 4; j++) {
                    bf16x8 bfr = *(const bf16x8*)(XT + (j * 16 + lm) * 72 + ks * 32 + quad * 8);
                    acc[i][j] = __builtin_amdgcn_mfma_f32_16x16x32_bf16(af, bfr, acc[i][j], 0, 0, 0);
                }
            }
        }
    }

    // ---- epilogue ----
    float dsk = D_skip[h];
    for (int i = 0; i < 4; i++)
        for (int r = 0; r < 4; r++) {
            int grow = row0 + wt + i * 16 + quad * 4 + r;
            const u16* xrow = xbc + (size_t)grow * CDIM + h * HD;
            u16* yrow = y + (size_t)grow * DI + h * HD;
            for (int j = 0; j < 4; j++) {
                int p = j * 16 + lm;
                yrow[p] = f2bf(acc[i][j][r] + dsk * bf2f(xrow[p]));
            }
        }
}

// ---- 8: out = (y * silu(z)) * rsqrt(mean(yg^2)+eps) * norm_w — vectorized ----
__global__ void final_kernel(const u16* __restrict__ y, const u16* __restrict__ zx,
                             const float* __restrict__ norm_w, float* __restrict__ out) {
    int row = blockIdx.x;
    int tid = threadIdx.x;
    int col0 = tid * 16;
    __shared__ float red[4];
    float yg[16];
    float ss = 0.f;
    {
        bf16x8 zv0 = *(const bf16x8*)(zx + (size_t)row * NP + col0);
        bf16x8 zv1 = *(const bf16x8*)(zx + (size_t)row * NP + col0 + 8);
        bf16x8 yv0 = *(const bf16x8*)(y  + (size_t)row * DI + col0);
        bf16x8 yv1 = *(const bf16x8*)(y  + (size_t)row * DI + col0 + 8);
        for (int e = 0; e < 8; e++) {
            float z = bf2f((u16)zv0[e]);
            float g = bf2f((u16)yv0[e]) * (z / (1.f + expf(-z)));
            yg[e] = g; ss += g * g;
        }
        for (int e = 0; e < 8; e++) {
            float z = bf2f((u16)zv1[e]);
            float g = bf2f((u16)yv1[e]) * (z / (1.f + expf(-z)));
            yg[8 + e] = g; ss += g * g;
        }
    }
    for (int off = 32; off; off >>= 1) ss += __shfl_down(ss, off);
    if ((tid & 63) == 0) red[tid >> 6] = ss;
    __syncthreads();
    if (tid == 0) red[0] = red[0] + red[1] + red[2] + red[3];
    __syncthreads();
    float inv = rsqrtf(red[0] / (float)DI + 1e-5f);
    for (int q = 0; q < 4; q++) {
        float4 nw = *(const float4*)(norm_w + col0 + q * 4);
        float4 o;
        o.x = yg[q * 4 + 0] * inv * nw.x;
        o.y = yg[q * 4 + 1] * inv * nw.y;
        o.z = yg[q * 4 + 2] * inv * nw.z;
        o.w = yg[q * 4 + 3] * inv * nw.w;
        *(float4*)(out + (size_t)row * DI + col0 + q * 4) = o;
    }
}

extern "C" void kernel_launch(void* const* d_in, const int* in_sizes, int n_in,
                              void* d_out, int out_size, void* d_ws, size_t ws_size,
                              hipStream_t stream) {
    const float* u       = (const float*)d_in[0];
    const float* w_in    = (const float*)d_in[1];
    const float* conv_w  = (const float*)d_in[2];
    const float* conv_b  = (const float*)d_in[3];
    const float* dt_bias = (const float*)d_in[4];
    const float* A_log   = (const float*)d_in[5];
    const float* D_skip  = (const float*)d_in[6];
    const float* norm_w  = (const float*)d_in[7];
    float* out = (float*)d_out;

    const size_t NEEDED = 179306496ull;   // layout unchanged
    if (ws_size < NEEDED) return;

    char* ws = (char*)d_ws;
    const size_t R = 70254592ull;
    u16*   zx   = (u16*)ws;                         // 70,254,592
    u16*   ubf  = (u16*)(ws + R);                   // GEMM phase
    u16*   wtb  = (u16*)(ws + R + 16777216);        // GEMM phase (NP2 x DM bf16 = 35.65MB,
                                                    //  overlaps post-GEMM buffers — phase-safe)
    u16*   xbc  = (u16*)(ws + R);                   // post-GEMM, 35,651,584
    float* dtbT = (float*)(ws + R + 35651584);      // 1 MB  [h][row]
    float* acs  = (float*)(ws + R + 36700160);      // 1 MB
    u16*   Gb   = (u16*)(ws + R + 37748736);        // 2 MB  masked bf16
    u16*   BmT  = (u16*)(ws + R + 39845888);        // 1 MB  [n][row]
    float* stat = (float*)(ws + R + 41943040);      // 33.5 MB
    u16*   yb   = (u16*)(ws + R + 75497472);        // 33.5 MB

    cvt_u_kernel<<<8192, 256, 0, stream>>>(u, ubf);
    transpose_w_kernel<<<dim3(272, 64), 256, 0, stream>>>(w_in, wtb);
    gemm_kernel<<<G_NBLK, 512, 0, stream>>>(ubf, wtb, zx);
    conv_silu_kernel<<<dim3(17, 256), 512, 0, stream>>>(zx, conv_w, conv_b, xbc);
    dt_scan_kernel<<<1024, 256, 0, stream>>>(zx, dt_bias, A_log, dtbT, acs);
    g_kernel<<<256, 256, 0, stream>>>(xbc, Gb);
    bmt_kernel<<<dim3(2, 64), 256, 0, stream>>>(xbc, BmT);
    states_kernel<<<1024, 256, 0, stream>>>(xbc, BmT, dtbT, acs, stat);
    cscan_kernel<<<128, 256, 0, stream>>>(stat, acs);
    y_kernel<<<1024, 256, 0, stream>>>(xbc, dtbT, acs, Gb, stat, D_skip, yb);
    final_kernel<<<4096, 256, 0, stream>>>(yb, zx, norm_w, out);
}

// Round 3
// 627.172 us; speedup vs baseline: 1.0162x; 1.0162x over previous
//
#include <hip/hip_runtime.h>
#include <hip/hip_bf16.h>

// ---- problem constants ----
#define B_SZ   2
#define L_SZ   2048
#define DM     2048
#define DS     128
#define DCV    4
#define HD     64
#define CH     256
#define DI     4096
#define NH     64
#define DIP    8512
#define CDIM   4352
#define NP     8576      // DIP padded to 67*128 (zx row stride)
#define NP2    8704      // GEMM N padded to 34*256 (wtb rows only)
#define MROWS  4096      // B_SZ*L_SZ
#define NCK    8         // L_SZ/CH

typedef __attribute__((ext_vector_type(8))) short bf16x8;
typedef __attribute__((ext_vector_type(4))) float f32x4;
typedef unsigned short u16;

__device__ __forceinline__ u16 f2bf(float f) {
    union { float f; unsigned u; } c; c.f = f;
    unsigned r = c.u + 0x7fffu + ((c.u >> 16) & 1u);
    return (u16)(r >> 16);
}
__device__ __forceinline__ float bf2f(u16 b) {
    union { unsigned u; float f; } c; c.u = ((unsigned)b) << 16; return c.f;
}

// async global->LDS copy, 16 B per lane (global_load_lds_dwordx4)
__device__ __forceinline__ void async16(const u16* g, u16* l) {
    __builtin_amdgcn_global_load_lds(
        (const __attribute__((address_space(1))) unsigned int*)(g),
        (__attribute__((address_space(3))) unsigned int*)(l),
        16, 0, 0);
}

// ---- 0a: u f32 -> bf16 ----
__global__ void cvt_u_kernel(const float* __restrict__ u, u16* __restrict__ ub) {
    int i = blockIdx.x * 256 + threadIdx.x;
    float4 v = ((const float4*)u)[i];
    ushort4 o;
    o.x = f2bf(v.x); o.y = f2bf(v.y); o.z = f2bf(v.z); o.w = f2bf(v.w);
    ((ushort4*)ub)[i] = o;
}

// ---- 0b: w_in (K=2048 x DIP) f32 -> w_inT (NP2 x K) bf16, zero-pad rows >= DIP ----
__global__ void transpose_w_kernel(const float* __restrict__ w, u16* __restrict__ wt) {
    __shared__ float tile[32][33];
    int n0 = blockIdx.x * 32, k0 = blockIdx.y * 32;
    int tx = threadIdx.x & 31, ty = threadIdx.x >> 5;
    for (int j = 0; j < 32; j += 8) {
        int k = k0 + ty + j, n = n0 + tx;
        tile[ty + j][tx] = (n < DIP) ? w[(size_t)k * DIP + n] : 0.f;
    }
    __syncthreads();
    for (int j = 0; j < 32; j += 8) {
        int n = n0 + ty + j, k = k0 + tx;
        wt[(size_t)n * DM + k] = f2bf(tile[tx][ty + j]);
    }
}

// ---- 1: GEMM zxbcdt = u @ w_in -> bf16 [MROWS][NP] ----
// 256x256 tile, BK=32, 8 waves (2Mx4N, 128x64 each => 0.375 ds_reads/MFMA),
// TRIPLE-buffered LDS (96KB), counted vmcnt(4) (never drains in main loop),
// 2 phases/K-tile, FIXED swizzle: granule ^= (row>>1)&3 so a 16-lane frag read
// spans 8 distinct bank-quads (2 lanes each = conflict-free; round-2's (row&3)
// gave only 4 quads = 4-way conflict, 1.34e7 SQ_LDS_BANK_CONFLICT).
#define G_NKT   64        // 2048/32 K-tiles
#define G_NBLK  544       // 16 * 34
__global__ __launch_bounds__(512) void gemm_kernel(const u16* __restrict__ A,
                                                   const u16* __restrict__ Bt,
                                                   u16* __restrict__ C) {
    __shared__ u16 As[3][256 * 32];   // 48 KB
    __shared__ u16 Bs[3][256 * 32];   // 48 KB

    int bid = blockIdx.x;
    int bidx = (bid & 7) * (G_NBLK / 8) + (bid >> 3);   // XCD swizzle (544 % 8 == 0)
    const int width = 8 * 34;                           // GM * N-tiles
    int group = bidx / width;
    int rem = bidx - group * width;
    int pid_m = group * 8 + (rem & 7);
    int pid_n = rem >> 3;
    const int m0 = pid_m * 256, n0 = pid_n * 256;

    const int tid = threadIdx.x;
    const int lane = tid & 63;
    const int wid = tid >> 6;
    const int wm = (wid >> 2) * 128;  // 0,128
    const int wn = (wid & 3) * 64;    // 0,64,128,192
    const int quad = lane >> 4, lm = lane & 15;

    // staging geometry: 512 threads cover 128 rows x 32 cols (8 KB) per issue
    const int srow = tid >> 2;                       // 0..127
    const int c4 = tid & 3;
    const int scol = (c4 ^ ((srow >> 1) & 3)) * 8;   // pre-swizzled source col chunk (u16)
    const u16* aS = A  + (size_t)(m0 + srow) * DM + scol;
    const u16* bS = Bt + (size_t)(n0 + srow) * DM + scol;
    const int ldo = srow * 32 + c4 * 8;              // linear LDS dest (= tid*16B)

    f32x4 acc[8][4] = {};

    // ---- prologue: tile0 -> buf0, tile1 -> buf1 (4 issues each) ----
    for (int t = 0; t < 2; t++) {
        const u16* as = aS + t * 32;
        const u16* bs = bS + t * 32;
        async16(as,                    &As[t][ldo]);
        async16(as + (size_t)128 * DM, &As[t][ldo + 4096]);
        async16(bs,                    &Bs[t][ldo]);
        async16(bs + (size_t)128 * DM, &Bs[t][ldo + 4096]);
    }
    asm volatile("s_waitcnt vmcnt(4)" ::: "memory");    // tile0 landed, tile1 in flight
    __builtin_amdgcn_s_barrier();

    for (int kt = 0; kt < G_NKT; kt++) {
        unsigned cur = (unsigned)kt % 3u;
        unsigned sb  = (unsigned)(kt + 2) % 3u;
        const bool dost = (kt + 2) < G_NKT;
        const u16* ab = &As[cur][0];
        const u16* bb = &Bs[cur][0];
        const u16* as = aS + (kt + 2) * 32;
        const u16* bs = bS + (kt + 2) * 32;

        // ---- phase 0: A-frags i0-3 + all B-frags ; stage A(t+2) ; 16 MFMA ----
        bf16x8 af[4], bfr[4];
        for (int i = 0; i < 4; i++) {
            int row = wm + i * 16 + lm;
            af[i] = *(const bf16x8*)(ab + row * 32 + ((quad ^ ((row >> 1) & 3)) * 8));
        }
        for (int j = 0; j < 4; j++) {
            int row = wn + j * 16 + lm;
            bfr[j] = *(const bf16x8*)(bb + row * 32 + ((quad ^ ((row >> 1) & 3)) * 8));
        }
        if (dost) {
            async16(as,                    &As[sb][ldo]);
            async16(as + (size_t)128 * DM, &As[sb][ldo + 4096]);
        }
        __builtin_amdgcn_s_barrier();
        asm volatile("s_waitcnt lgkmcnt(0)" ::: "memory");
        __builtin_amdgcn_s_setprio(1);
        for (int i = 0; i < 4; i++)
            for (int j = 0; j < 4; j++)
                acc[i][j] = __builtin_amdgcn_mfma_f32_16x16x32_bf16(af[i], bfr[j], acc[i][j], 0, 0, 0);
        __builtin_amdgcn_s_setprio(0);
        __builtin_amdgcn_s_barrier();

        // ---- phase 1: A-frags i4-7 ; stage B(t+2) ; counted vmcnt ; 16 MFMA (B reused) ----
        bf16x8 ag[4];
        for (int i = 0; i < 4; i++) {
            int row = wm + 64 + i * 16 + lm;
            ag[i] = *(const bf16x8*)(ab + row * 32 + ((quad ^ ((row >> 1) & 3)) * 8));
        }
        if (dost) {
            async16(bs,                    &Bs[sb][ldo]);
            async16(bs + (size_t)128 * DM, &Bs[sb][ldo + 4096]);
        }
        if (kt < G_NKT - 2) { asm volatile("s_waitcnt vmcnt(4)" ::: "memory"); }
        else                { asm volatile("s_waitcnt vmcnt(0)" ::: "memory"); }
        __builtin_amdgcn_s_barrier();
        asm volatile("s_waitcnt lgkmcnt(0)" ::: "memory");
        __builtin_amdgcn_s_setprio(1);
        for (int i = 0; i < 4; i++)
            for (int j = 0; j < 4; j++)
                acc[i + 4][j] = __builtin_amdgcn_mfma_f32_16x16x32_bf16(ag[i], bfr[j], acc[i + 4][j], 0, 0, 0);
        __builtin_amdgcn_s_setprio(0);
        __builtin_amdgcn_s_barrier();
    }

    for (int i = 0; i < 8; i++)
        for (int j = 0; j < 4; j++)
            for (int r = 0; r < 4; r++) {
                int gm = m0 + wm + i * 16 + quad * 4 + r;
                int gn = n0 + wn + j * 16 + lm;
                if (gn < NP)
                    C[(size_t)gm * NP + gn] = f2bf(acc[i][j][r]);
            }
}

// ---- 2: causal depthwise conv(4) + SiLU — vectorized, 8 channels/thread ----
__global__ void conv_silu_kernel(const u16* __restrict__ zx, const float* __restrict__ cw,
                                 const float* __restrict__ cb, u16* __restrict__ xbc) {
    int tid = threadIdx.x;
    int c8  = blockIdx.x * 32 + (tid & 31);        // 0..543
    int row = blockIdx.y * 16 + (tid >> 5);        // 0..4095
    int c0  = c8 * 8;
    int l = row & (L_SZ - 1);

    float w_[8][4];
    {
        const float4* wp = (const float4*)(cw + (size_t)c0 * 4);
        for (int e = 0; e < 8; e++) {
            float4 v = wp[e];
            w_[e][0] = v.x; w_[e][1] = v.y; w_[e][2] = v.z; w_[e][3] = v.w;
        }
    }
    float acc[8];
    {
        float4 b0 = *(const float4*)(cb + c0);
        float4 b1 = *(const float4*)(cb + c0 + 4);
        acc[0] = b0.x; acc[1] = b0.y; acc[2] = b0.z; acc[3] = b0.w;
        acc[4] = b1.x; acc[5] = b1.y; acc[6] = b1.z; acc[7] = b1.w;
    }
    for (int k = 0; k < DCV; k++) {
        int ls = l - 3 + k;
        if (ls >= 0) {
            bf16x8 v = *(const bf16x8*)(zx + (size_t)(row - 3 + k) * NP + DI + c0);
            for (int e = 0; e < 8; e++)
                acc[e] += bf2f((u16)v[e]) * w_[e][k];
        }
    }
    bf16x8 o;
    for (int e = 0; e < 8; e++) {
        float s = acc[e] / (1.f + expf(-acc[e]));
        o[e] = (short)f2bf(s);
    }
    *(bf16x8*)(xbc + (size_t)row * CDIM + c0) = o;
}

// ---- 3: dt = softplus(raw+bias) -> dtbT[h][row]; per-chunk cumsum of dA -> acs ----
__global__ void dt_scan_kernel(const u16* __restrict__ zx, const float* __restrict__ dt_bias,
                               const float* __restrict__ A_log, float* __restrict__ dtbT,
                               float* __restrict__ acs) {
    int bid = blockIdx.x;
    int h = bid & 63, c = (bid >> 6) & 7, b = bid >> 9;
    int t = threadIdx.x;
    int row = b * L_SZ + c * CH + t;
    float raw = bf2f(zx[(size_t)row * NP + (DI + CDIM) + h]) + dt_bias[h];
    float dtv = (raw > 20.f) ? raw : log1pf(expf(raw));
    float dA = dtv * (-expf(A_log[h]));
    dtbT[(size_t)h * MROWS + row] = dtv;
    __shared__ float sc[256];
    sc[t] = dA;
    for (int off = 1; off < 256; off <<= 1) {
        __syncthreads();
        float v = (t >= off) ? sc[t - off] : 0.f;
        __syncthreads();
        sc[t] += v;
    }
    acs[((size_t)((b * NH + h) * NCK + c)) * CH + t] = sc[t];
}

// ---- 4: Gb[t][s] = masked bf16( sum_n Cm[t,n]*Bm[s,n] ) per (b,c) ----
__global__ void g_kernel(const u16* __restrict__ xbc, u16* __restrict__ Gb) {
    int blk = blockIdx.x;
    int bc = blk >> 4;
    int tile = blk & 15;
    int tb0 = (tile >> 2) * 64, sb0 = (tile & 3) * 64;
    int row0 = bc * CH;
    __shared__ float Ct[64][65], Bt_[64][65];
    int tq = (threadIdx.x >> 4) * 4;
    int sq = (threadIdx.x & 15) * 4;
    float acc[4][4] = {};
    for (int nh = 0; nh < 2; nh++) {
        __syncthreads();
        int r = threadIdx.x >> 2, cc = (threadIdx.x & 3) * 16;
        for (int q = 0; q < 16; q += 4) {
            ushort4 cv = *(const ushort4*)&xbc[(size_t)(row0 + tb0 + r) * CDIM + (DI + DS) + nh * 64 + cc + q];
            ushort4 bv = *(const ushort4*)&xbc[(size_t)(row0 + sb0 + r) * CDIM + DI + nh * 64 + cc + q];
            Ct[r][cc + q] = bf2f(cv.x); Ct[r][cc + q + 1] = bf2f(cv.y); Ct[r][cc + q + 2] = bf2f(cv.z); Ct[r][cc + q + 3] = bf2f(cv.w);
            Bt_[r][cc + q] = bf2f(bv.x); Bt_[r][cc + q + 1] = bf2f(bv.y); Bt_[r][cc + q + 2] = bf2f(bv.z); Bt_[r][cc + q + 3] = bf2f(bv.w);
        }
        __syncthreads();
        for (int n = 0; n < 64; n++) {
            float a[4], bb[4];
            for (int i = 0; i < 4; i++) a[i] = Ct[tq + i][n];
            for (int j = 0; j < 4; j++) bb[j] = Bt_[sq + j][n];
            for (int i = 0; i < 4; i++)
                for (int j = 0; j < 4; j++) acc[i][j] += a[i] * bb[j];
        }
    }
    for (int i = 0; i < 4; i++)
        for (int j = 0; j < 4; j++) {
            int t = tb0 + tq + i, s = sb0 + sq + j;
            Gb[((size_t)(bc * CH + t)) * CH + s] = (s <= t) ? f2bf(acc[i][j]) : (u16)0;
        }
}

// ---- 4b: BmT[n][row] = xbc[row][DI+n]  (128 x 4096 bf16) ----
__global__ void bmt_kernel(const u16* __restrict__ xbc, u16* __restrict__ BmT) {
    __shared__ u16 tile[64 * 72];
    int n0 = blockIdx.x * 64, r0 = blockIdx.y * 64;
    int tid = threadIdx.x;
    {
        int r = tid >> 2, seg = (tid & 3) * 16;
        const u16* src = xbc + (size_t)(r0 + r) * CDIM + DI + n0 + seg;
        *(int4*)(tile + r * 72 + seg)     = *(const int4*)(src);
        *(int4*)(tile + r * 72 + seg + 8) = *(const int4*)(src + 8);
    }
    __syncthreads();
    {
        int n = tid >> 2, seg = (tid & 3) * 16;
        union { u16 v[16]; int4 q[2]; } o;
        for (int q = 0; q < 16; q++) o.v[q] = tile[(seg + q) * 72 + n];
        u16* dst = BmT + (size_t)(n0 + n) * MROWS + r0 + seg;
        *(int4*)(dst)     = o.q[0];
        *(int4*)(dst + 8) = o.q[1];
    }
}

// ---- 5: states[p][n] = sum_t (X[t,p]*dt[t]*decay[t]) * Bm[t,n]  per (b,c,h) — MFMA ----
__global__ __launch_bounds__(256) void states_kernel(const u16* __restrict__ xbc, const u16* __restrict__ BmT,
                                                     const float* __restrict__ dtbT, const float* __restrict__ acs_g,
                                                     float* __restrict__ states) {
    int bid = blockIdx.x;                 // (b,c,h)
    int h = bid & 63, c = (bid >> 6) & 7, b = bid >> 9;
    int row0 = b * L_SZ + c * CH;
    int tid = threadIdx.x;
    int lane = tid & 63, w = tid >> 6;
    int quad = lane >> 4, lm = lane & 15;
    int mh = (w >> 1) * 32, nh = (w & 1) * 64;

    __shared__ float wsc[CH];
    __shared__ u16 XTs[64 * 136];         // [p][t_local], pad 136

    {
        size_t abase = ((size_t)((b * NH + h) * NCK + c)) * CH;
        float a255 = acs_g[abase + 255];
        float at = acs_g[abase + tid];
        wsc[tid] = dtbT[(size_t)h * MROWS + row0 + tid] * expf(a255 - at);
    }
    f32x4 acc[2][4] = {};
    for (int k0 = 0; k0 < CH; k0 += 128) {
        __syncthreads();
        {   // stage scaled-transposed X chunk: thread -> (t row, 32 p)
            int tl = tid >> 1;            // 0..127
            int pseg = (tid & 1) * 32;
            float wv = wsc[k0 + tl];
            const u16* xr = xbc + (size_t)(row0 + k0 + tl) * CDIM + h * HD + pseg;
            for (int q4 = 0; q4 < 4; q4++) {
                bf16x8 v = *(const bf16x8*)(xr + q4 * 8);
                for (int e = 0; e < 8; e++)
                    XTs[(pseg + q4 * 8 + e) * 136 + tl] = f2bf(bf2f((u16)v[e]) * wv);
            }
        }
        __syncthreads();
        for (int ks = 0; ks < 4; ks++) {
            bf16x8 af[2];
            for (int i = 0; i < 2; i++)
                af[i] = *(const bf16x8*)(XTs + (mh + i * 16 + lm) * 136 + ks * 32 + quad * 8);
            for (int j = 0; j < 4; j++) {
                const u16* brow = BmT + (size_t)(nh + j * 16 + lm) * MROWS + row0 + k0 + ks * 32 + quad * 8;
                bf16x8 bfr = *(const bf16x8*)brow;
                for (int i = 0; i < 2; i++)
                    acc[i][j] = __builtin_amdgcn_mfma_f32_16x16x32_bf16(af[i], bfr, acc[i][j], 0, 0, 0);
            }
        }
    }
    float* st = states + (size_t)bid * (HD * DS);
    for (int i = 0; i < 2; i++)
        for (int j = 0; j < 4; j++)
            for (int r = 0; r < 4; r++) {
                int p = mh + i * 16 + quad * 4 + r;
                int n = nh + j * 16 + lm;
                st[p * DS + n] = acc[i][j][r];
            }
}

// ---- 6: inter-chunk scan IN PLACE ----
__global__ void cscan_kernel(float* __restrict__ states, const float* __restrict__ acs_g) {
    int bid = blockIdx.x;
    int h = bid & 63, b = bid >> 6;
    int tid = threadIdx.x;
    float4 carry[8];
    for (int i = 0; i < 8; i++) carry[i] = make_float4(0.f, 0.f, 0.f, 0.f);
    for (int c = 0; c < NCK; c++) {
        size_t base = ((size_t)((b * NCK + c) * NH + h)) * (HD * DS);
        float g = expf(acs_g[((size_t)((b * NH + h) * NCK + c)) * CH + (CH - 1)]);
        float4* sp = (float4*)(states + base);
        for (int i = 0; i < 8; i++) {
            int idx = tid + 256 * i;
            float4 s = sp[idx];
            sp[idx] = carry[i];
            carry[i].x = carry[i].x * g + s.x;
            carry[i].y = carry[i].y * g + s.y;
            carry[i].z = carry[i].z * g + s.z;
            carry[i].w = carry[i].w * g + s.w;
        }
    }
}

// ---- 7: y = Yo + Yd + D_skip*x per (b,c,h) — MFMA, register-built Yd A-frags ----
__global__ __launch_bounds__(256) void y_kernel(const u16* __restrict__ xbc, const float* __restrict__ dtbT,
                                                const float* __restrict__ acs_g, const u16* __restrict__ Gb,
                                                const float* __restrict__ init_st, const float* __restrict__ D_skip,
                                                u16* __restrict__ y) {
    int bid = blockIdx.x;                 // (b,c,h)
    int h = bid & 63, c = (bid >> 6) & 7, b = bid >> 9;
    int bc = b * NCK + c;
    int row0 = b * L_SZ + c * CH;
    int tid = threadIdx.x;
    int lane = tid & 63, w = tid >> 6;
    int wt = w * 64;
    int quad = lane >> 4, lm = lane & 15;

    __shared__ float acs[CH];             // 1 KB
    __shared__ u16 Ssb[64 * 136];         // 17.4 KB  states bf16 [p][n] pad 136
    __shared__ u16 XT[64 * 72];           // 9.2 KB   Xdt^T [p][s_local] pad 72

    acs[tid] = acs_g[((size_t)((b * NH + h) * NCK + c)) * CH + tid];
    {   // init_st f32 [p][n] -> bf16 LDS padded
        const float4* sg = (const float4*)(init_st + ((size_t)(bc * NH + h)) * (HD * DS));
        for (int i = 0; i < 8; i++) {
            int g = tid + 256 * i;
            int p = g >> 5, n4 = (g & 31) * 4;
            float4 v = sg[g];
            ushort4 o;
            o.x = f2bf(v.x); o.y = f2bf(v.y); o.z = f2bf(v.z); o.w = f2bf(v.w);
            *(ushort4*)(Ssb + p * 136 + n4) = o;
        }
    }
    __syncthreads();

    f32x4 acc[4][4] = {};
    // ---- Yo: A = raw Cm rows from global; B = Ssb ----
    for (int i = 0; i < 4; i++) {
        const u16* arow = xbc + (size_t)(row0 + wt + i * 16 + lm) * CDIM + (DI + DS);
        for (int ks = 0; ks < 4; ks++) {
            bf16x8 af = *(const bf16x8*)(arow + ks * 32 + quad * 8);
            for (int j = 0; j < 4; j++) {
                bf16x8 bfr = *(const bf16x8*)(Ssb + (j * 16 + lm) * 136 + ks * 32 + quad * 8);
                acc[i][j] = __builtin_amdgcn_mfma_f32_16x16x32_bf16(af, bfr, acc[i][j], 0, 0, 0);
            }
        }
    }
    for (int i = 0; i < 4; i++) {
        float et[4];
        for (int r = 0; r < 4; r++) et[r] = expf(acs[wt + i * 16 + quad * 4 + r]);
        for (int j = 0; j < 4; j++)
            for (int r = 0; r < 4; r++) acc[i][j][r] *= et[r];
    }

    // ---- Yd: A-frag built in registers from masked Gb + exp; B = XT (dt folded) ----
    const u16* gball = Gb + (size_t)bc * CH * CH;
    for (int s0 = 0; s0 < CH; s0 += 64) {
        __syncthreads();
        {   // XT[p][s_local] = x[s][p] * dt[s]
            int r = tid >> 2, cseg = (tid & 3) * 16;
            int row = row0 + s0 + r;
            float dv = dtbT[(size_t)h * MROWS + row];
            const u16* xr = xbc + (size_t)row * CDIM + h * HD + cseg;
            for (int q8 = 0; q8 < 2; q8++) {
                bf16x8 v = *(const bf16x8*)(xr + q8 * 8);
                for (int e = 0; e < 8; e++)
                    XT[(cseg + q8 * 8 + e) * 72 + r] = f2bf(bf2f((u16)v[e]) * dv);
            }
        }
        __syncthreads();
        if (wt + 63 < s0) continue;
        for (int i = 0; i < 4; i++) {
            int tTop = wt + i * 16 + 15;
            if (tTop < s0) continue;
            int t = wt + i * 16 + lm;
            float at = acs[t];
            const u16* grow_ = gball + (size_t)t * CH + s0;
            for (int ks = 0; ks < 2; ks++) {
                if (s0 + ks * 32 > tTop) continue;
                bf16x8 g8 = *(const bf16x8*)(grow_ + ks * 32 + quad * 8);
                const float* asp = &acs[s0 + ks * 32 + quad * 8];
                bf16x8 af;
                for (int e = 0; e < 8; e++) {
                    float m = bf2f((u16)g8[e]) * expf(fminf(at - asp[e], 0.f));
                    af[e] = (short)f2bf(m);
                }
                for (int j = 0; j < 4; j++) {
                    bf16x8 bfr = *(const bf16x8*)(XT + (j * 16 + lm) * 72 + ks * 32 + quad * 8);
                    acc[i][j] = __builtin_amdgcn_mfma_f32_16x16x32_bf16(af, bfr, acc[i][j], 0, 0, 0);
                }
            }
        }
    }

    // ---- epilogue ----
    float dsk = D_skip[h];
    for (int i = 0; i < 4; i++)
        for (int r = 0; r < 4; r++) {
            int grow = row0 + wt + i * 16 + quad * 4 + r;
            const u16* xrow = xbc + (size_t)grow * CDIM + h * HD;
            u16* yrow = y + (size_t)grow * DI + h * HD;
            for (int j = 0; j < 4; j++) {
                int p = j * 16 + lm;
                yrow[p] = f2bf(acc[i][j][r] + dsk * bf2f(xrow[p]));
            }
        }
}

// ---- 8: out = (y * silu(z)) * rsqrt(mean(yg^2)+eps) * norm_w — vectorized ----
__global__ void final_kernel(const u16* __restrict__ y, const u16* __restrict__ zx,
                             const float* __restrict__ norm_w, float* __restrict__ out) {
    int row = blockIdx.x;
    int tid = threadIdx.x;
    int col0 = tid * 16;
    __shared__ float red[4];
    float yg[16];
    float ss = 0.f;
    {
        bf16x8 zv0 = *(const bf16x8*)(zx + (size_t)row * NP + col0);
        bf16x8 zv1 = *(const bf16x8*)(zx + (size_t)row * NP + col0 + 8);
        bf16x8 yv0 = *(const bf16x8*)(y  + (size_t)row * DI + col0);
        bf16x8 yv1 = *(const bf16x8*)(y  + (size_t)row * DI + col0 + 8);
        for (int e = 0; e < 8; e++) {
            float z = bf2f((u16)zv0[e]);
            float g = bf2f((u16)yv0[e]) * (z / (1.f + expf(-z)));
            yg[e] = g; ss += g * g;
        }
        for (int e = 0; e < 8; e++) {
            float z = bf2f((u16)zv1[e]);
            float g = bf2f((u16)yv1[e]) * (z / (1.f + expf(-z)));
            yg[8 + e] = g; ss += g * g;
        }
    }
    for (int off = 32; off; off >>= 1) ss += __shfl_down(ss, off);
    if ((tid & 63) == 0) red[tid >> 6] = ss;
    __syncthreads();
    if (tid == 0) red[0] = red[0] + red[1] + red[2] + red[3];
    __syncthreads();
    float inv = rsqrtf(red[0] / (float)DI + 1e-5f);
    for (int q = 0; q < 4; q++) {
        float4 nw = *(const float4*)(norm_w + col0 + q * 4);
        float4 o;
        o.x = yg[q * 4 + 0] * inv * nw.x;
        o.y = yg[q * 4 + 1] * inv * nw.y;
        o.z = yg[q * 4 + 2] * inv * nw.z;
        o.w = yg[q * 4 + 3] * inv * nw.w;
        *(float4*)(out + (size_t)row * DI + col0 + q * 4) = o;
    }
}

extern "C" void kernel_launch(void* const* d_in, const int* in_sizes, int n_in,
                              void* d_out, int out_size, void* d_ws, size_t ws_size,
                              hipStream_t stream) {
    const float* u       = (const float*)d_in[0];
    const float* w_in    = (const float*)d_in[1];
    const float* conv_w  = (const float*)d_in[2];
    const float* conv_b  = (const float*)d_in[3];
    const float* dt_bias = (const float*)d_in[4];
    const float* A_log   = (const float*)d_in[5];
    const float* D_skip  = (const float*)d_in[6];
    const float* norm_w  = (const float*)d_in[7];
    float* out = (float*)d_out;

    const size_t NEEDED = 179306496ull;   // layout unchanged
    if (ws_size < NEEDED) return;

    char* ws = (char*)d_ws;
    const size_t R = 70254592ull;
    u16*   zx   = (u16*)ws;                         // 70,254,592
    u16*   ubf  = (u16*)(ws + R);                   // GEMM phase
    u16*   wtb  = (u16*)(ws + R + 16777216);        // GEMM phase (NP2 x DM bf16 = 35.65MB,
                                                    //  overlaps post-GEMM buffers — phase-safe)
    u16*   xbc  = (u16*)(ws + R);                   // post-GEMM, 35,651,584
    float* dtbT = (float*)(ws + R + 35651584);      // 1 MB  [h][row]
    float* acs  = (float*)(ws + R + 36700160);      // 1 MB
    u16*   Gb   = (u16*)(ws + R + 37748736);        // 2 MB  masked bf16
    u16*   BmT  = (u16*)(ws + R + 39845888);        // 1 MB  [n][row]
    float* stat = (float*)(ws + R + 41943040);      // 33.5 MB
    u16*   yb   = (u16*)(ws + R + 75497472);        // 33.5 MB

    cvt_u_kernel<<<8192, 256, 0, stream>>>(u, ubf);
    transpose_w_kernel<<<dim3(272, 64), 256, 0, stream>>>(w_in, wtb);
    gemm_kernel<<<G_NBLK, 512, 0, stream>>>(ubf, wtb, zx);
    conv_silu_kernel<<<dim3(17, 256), 512, 0, stream>>>(zx, conv_w, conv_b, xbc);
    dt_scan_kernel<<<1024, 256, 0, stream>>>(zx, dt_bias, A_log, dtbT, acs);
    g_kernel<<<256, 256, 0, stream>>>(xbc, Gb);
    bmt_kernel<<<dim3(2, 64), 256, 0, stream>>>(xbc, BmT);
    states_kernel<<<1024, 256, 0, stream>>>(xbc, BmT, dtbT, acs, stat);
    cscan_kernel<<<128, 256, 0, stream>>>(stat, acs);
    y_kernel<<<1024, 256, 0, stream>>>(xbc, dtbT, acs, Gb, stat, D_skip, yb);
    final_kernel<<<4096, 256, 0, stream>>>(yb, zx, norm_w, out);
}

// Round 4
// 532.818 us; speedup vs baseline: 1.1961x; 1.1771x over previous
//
#include <hip/hip_runtime.h>
#include <hip/hip_bf16.h>

// ---- problem constants ----
#define B_SZ   2
#define L_SZ   2048
#define DM     2048
#define DS     128
#define DCV    4
#define HD     64
#define CH     256
#define DI     4096
#define NH     64
#define DIP    8512
#define CDIM   4352
#define NP     8576      // DIP padded to 67*128
#define MROWS  4096      // B_SZ*L_SZ
#define NCK    8         // L_SZ/CH

typedef __attribute__((ext_vector_type(8))) short bf16x8;
typedef __attribute__((ext_vector_type(4))) float f32x4;
typedef unsigned short u16;

__device__ __forceinline__ u16 f2bf(float f) {
    union { float f; unsigned u; } c; c.f = f;
    unsigned r = c.u + 0x7fffu + ((c.u >> 16) & 1u);
    return (u16)(r >> 16);
}
__device__ __forceinline__ float bf2f(u16 b) {
    union { unsigned u; float f; } c; c.u = ((unsigned)b) << 16; return c.f;
}

// async global->LDS copy, 16 B per lane (global_load_lds_dwordx4)
__device__ __forceinline__ void async16(const u16* g, u16* l) {
    __builtin_amdgcn_global_load_lds(
        (const __attribute__((address_space(1))) unsigned int*)(g),
        (__attribute__((address_space(3))) unsigned int*)(l),
        16, 0, 0);
}

// ---- 0a: u f32 -> bf16 ----
__global__ void cvt_u_kernel(const float* __restrict__ u, u16* __restrict__ ub) {
    int i = blockIdx.x * 256 + threadIdx.x;
    float4 v = ((const float4*)u)[i];
    ushort4 o;
    o.x = f2bf(v.x); o.y = f2bf(v.y); o.z = f2bf(v.z); o.w = f2bf(v.w);
    ((ushort4*)ub)[i] = o;
}

// ---- 0b: w_in (K=2048 x DIP) f32 -> w_inT (NP x K) bf16, zero-pad rows >= DIP ----
__global__ void transpose_w_kernel(const float* __restrict__ w, u16* __restrict__ wt) {
    __shared__ float tile[32][33];
    int n0 = blockIdx.x * 32, k0 = blockIdx.y * 32;
    int tx = threadIdx.x & 31, ty = threadIdx.x >> 5;
    for (int j = 0; j < 32; j += 8) {
        int k = k0 + ty + j, n = n0 + tx;
        tile[ty + j][tx] = (n < DIP) ? w[(size_t)k * DIP + n] : 0.f;
    }
    __syncthreads();
    for (int j = 0; j < 32; j += 8) {
        int n = n0 + ty + j, k = k0 + tx;
        wt[(size_t)n * DM + k] = f2bf(tile[tx][ty + j]);
    }
}

// ---- 1: GEMM zxbcdt = u @ w_in -> bf16 [MROWS][NP] ----
// Round-0 proven kernel (128^2 tile, m97+grouped-M+XOR swizzle, 822 TF here)
// + ONE change: XCD-aware bid swizzle (T1). 2144 % 8 == 0 -> bijective.
#define GEMM_NM 32
#define GEMM_NN 67
#define GEMM_GM 8
__global__ __launch_bounds__(256) void gemm_kernel(const u16* __restrict__ A,
                                                   const u16* __restrict__ Bt,
                                                   u16* __restrict__ C) {
    __shared__ u16 As[128 * 64];
    __shared__ u16 Bs[128 * 64];
    const int bid0 = blockIdx.x;
    const int bid = (bid0 & 7) * ((GEMM_NM * GEMM_NN) / 8) + (bid0 >> 3);  // XCD swizzle
    const int width = GEMM_GM * GEMM_NN;
    const int group = bid / width;
    const int rem = bid - group * width;
    const int pid_m = group * GEMM_GM + (rem % GEMM_GM);
    const int pid_n = rem / GEMM_GM;
    const int m0 = pid_m * 128, n0 = pid_n * 128;

    const int tid = threadIdx.x;
    const int lane = tid & 63, w = tid >> 6;
    const int wm = (w >> 1) * 64, wn = (w & 1) * 64;
    const int quad = lane >> 4, lm = lane & 15;
    const int lr = lane >> 3;
    const int pc = lane & 7;
    const int lcl = ((pc ^ lr) * 8);
    const int sx = (lm & 7);
    f32x4 acc[4][4] = {};
    for (int k0 = 0; k0 < DM; k0 += 64) {
        __syncthreads();
        for (int j = 0; j < 4; j++) {
            int row = w * 32 + j * 8 + lr;
            async16(A  + (size_t)(m0 + row) * DM + k0 + lcl, As + row * 64 + pc * 8);
            async16(Bt + (size_t)(n0 + row) * DM + k0 + lcl, Bs + row * 64 + pc * 8);
        }
        __syncthreads();
        for (int half = 0; half < 2; half++) {
            int cq = half * 4 + quad;
            int co = (cq ^ sx) * 8;
            bf16x8 af[4], bfr[4];
            for (int i = 0; i < 4; i++) af[i]  = *(const bf16x8*)(As + (wm + i * 16 + lm) * 64 + co);
            for (int j = 0; j < 4; j++) bfr[j] = *(const bf16x8*)(Bs + (wn + j * 16 + lm) * 64 + co);
            for (int i = 0; i < 4; i++)
                for (int j = 0; j < 4; j++)
                    acc[i][j] = __builtin_amdgcn_mfma_f32_16x16x32_bf16(af[i], bfr[j], acc[i][j], 0, 0, 0);
        }
    }
    for (int i = 0; i < 4; i++)
        for (int j = 0; j < 4; j++)
            for (int r = 0; r < 4; r++) {
                int gm = m0 + wm + i * 16 + quad * 4 + r;
                int gn = n0 + wn + j * 16 + lm;
                C[(size_t)gm * NP + gn] = f2bf(acc[i][j][r]);
            }
}

// ---- 2: causal depthwise conv(4) + SiLU — vectorized, 8 channels/thread ----
__global__ void conv_silu_kernel(const u16* __restrict__ zx, const float* __restrict__ cw,
                                 const float* __restrict__ cb, u16* __restrict__ xbc) {
    int tid = threadIdx.x;
    int c8  = blockIdx.x * 32 + (tid & 31);        // 0..543
    int row = blockIdx.y * 16 + (tid >> 5);        // 0..4095
    int c0  = c8 * 8;
    int l = row & (L_SZ - 1);

    float w_[8][4];
    {
        const float4* wp = (const float4*)(cw + (size_t)c0 * 4);
        for (int e = 0; e < 8; e++) {
            float4 v = wp[e];
            w_[e][0] = v.x; w_[e][1] = v.y; w_[e][2] = v.z; w_[e][3] = v.w;
        }
    }
    float acc[8];
    {
        float4 b0 = *(const float4*)(cb + c0);
        float4 b1 = *(const float4*)(cb + c0 + 4);
        acc[0] = b0.x; acc[1] = b0.y; acc[2] = b0.z; acc[3] = b0.w;
        acc[4] = b1.x; acc[5] = b1.y; acc[6] = b1.z; acc[7] = b1.w;
    }
    for (int k = 0; k < DCV; k++) {
        int ls = l - 3 + k;
        if (ls >= 0) {
            bf16x8 v = *(const bf16x8*)(zx + (size_t)(row - 3 + k) * NP + DI + c0);
            for (int e = 0; e < 8; e++)
                acc[e] += bf2f((u16)v[e]) * w_[e][k];
        }
    }
    bf16x8 o;
    for (int e = 0; e < 8; e++) {
        float s = acc[e] / (1.f + expf(-acc[e]));
        o[e] = (short)f2bf(s);
    }
    *(bf16x8*)(xbc + (size_t)row * CDIM + c0) = o;
}

// ---- 3: dt = softplus(raw+bias) -> dtbT[h][row]; per-chunk cumsum of dA -> acs ----
__global__ void dt_scan_kernel(const u16* __restrict__ zx, const float* __restrict__ dt_bias,
                               const float* __restrict__ A_log, float* __restrict__ dtbT,
                               float* __restrict__ acs) {
    int bid = blockIdx.x;
    int h = bid & 63, c = (bid >> 6) & 7, b = bid >> 9;
    int t = threadIdx.x;
    int row = b * L_SZ + c * CH + t;
    float raw = bf2f(zx[(size_t)row * NP + (DI + CDIM) + h]) + dt_bias[h];
    float dtv = (raw > 20.f) ? raw : log1pf(expf(raw));
    float dA = dtv * (-expf(A_log[h]));
    dtbT[(size_t)h * MROWS + row] = dtv;
    __shared__ float sc[256];
    sc[t] = dA;
    for (int off = 1; off < 256; off <<= 1) {
        __syncthreads();
        float v = (t >= off) ? sc[t - off] : 0.f;
        __syncthreads();
        sc[t] += v;
    }
    acs[((size_t)((b * NH + h) * NCK + c)) * CH + t] = sc[t];
}

// ---- 4: Gb[t][s] = masked bf16( sum_n Cm[t,n]*Bm[s,n] ) per (b,c) ----
__global__ void g_kernel(const u16* __restrict__ xbc, u16* __restrict__ Gb) {
    int blk = blockIdx.x;
    int bc = blk >> 4;
    int tile = blk & 15;
    int tb0 = (tile >> 2) * 64, sb0 = (tile & 3) * 64;
    int row0 = bc * CH;
    __shared__ float Ct[64][65], Bt_[64][65];
    int tq = (threadIdx.x >> 4) * 4;
    int sq = (threadIdx.x & 15) * 4;
    float acc[4][4] = {};
    for (int nh = 0; nh < 2; nh++) {
        __syncthreads();
        int r = threadIdx.x >> 2, cc = (threadIdx.x & 3) * 16;
        for (int q = 0; q < 16; q += 4) {
            ushort4 cv = *(const ushort4*)&xbc[(size_t)(row0 + tb0 + r) * CDIM + (DI + DS) + nh * 64 + cc + q];
            ushort4 bv = *(const ushort4*)&xbc[(size_t)(row0 + sb0 + r) * CDIM + DI + nh * 64 + cc + q];
            Ct[r][cc + q] = bf2f(cv.x); Ct[r][cc + q + 1] = bf2f(cv.y); Ct[r][cc + q + 2] = bf2f(cv.z); Ct[r][cc + q + 3] = bf2f(cv.w);
            Bt_[r][cc + q] = bf2f(bv.x); Bt_[r][cc + q + 1] = bf2f(bv.y); Bt_[r][cc + q + 2] = bf2f(bv.z); Bt_[r][cc + q + 3] = bf2f(bv.w);
        }
        __syncthreads();
        for (int n = 0; n < 64; n++) {
            float a[4], bb[4];
            for (int i = 0; i < 4; i++) a[i] = Ct[tq + i][n];
            for (int j = 0; j < 4; j++) bb[j] = Bt_[sq + j][n];
            for (int i = 0; i < 4; i++)
                for (int j = 0; j < 4; j++) acc[i][j] += a[i] * bb[j];
        }
    }
    for (int i = 0; i < 4; i++)
        for (int j = 0; j < 4; j++) {
            int t = tb0 + tq + i, s = sb0 + sq + j;
            Gb[((size_t)(bc * CH + t)) * CH + s] = (s <= t) ? f2bf(acc[i][j]) : (u16)0;
        }
}

// ---- 4b: BmT[n][row] = xbc[row][DI+n]  (128 x 4096 bf16) ----
__global__ void bmt_kernel(const u16* __restrict__ xbc, u16* __restrict__ BmT) {
    __shared__ u16 tile[64 * 72];
    int n0 = blockIdx.x * 64, r0 = blockIdx.y * 64;
    int tid = threadIdx.x;
    {
        int r = tid >> 2, seg = (tid & 3) * 16;
        const u16* src = xbc + (size_t)(r0 + r) * CDIM + DI + n0 + seg;
        *(int4*)(tile + r * 72 + seg)     = *(const int4*)(src);
        *(int4*)(tile + r * 72 + seg + 8) = *(const int4*)(src + 8);
    }
    __syncthreads();
    {
        int n = tid >> 2, seg = (tid & 3) * 16;
        union { u16 v[16]; int4 q[2]; } o;
        for (int q = 0; q < 16; q++) o.v[q] = tile[(seg + q) * 72 + n];
        u16* dst = BmT + (size_t)(n0 + n) * MROWS + r0 + seg;
        *(int4*)(dst)     = o.q[0];
        *(int4*)(dst + 8) = o.q[1];
    }
}

// ---- 5: states[p][n] = sum_t (X[t,p]*dt[t]*decay[t]) * Bm[t,n]  per (b,c,h) — MFMA ----
__global__ __launch_bounds__(256) void states_kernel(const u16* __restrict__ xbc, const u16* __restrict__ BmT,
                                                     const float* __restrict__ dtbT, const float* __restrict__ acs_g,
                                                     float* __restrict__ states) {
    int bid = blockIdx.x;                 // (b,c,h)
    int h = bid & 63, c = (bid >> 6) & 7, b = bid >> 9;
    int row0 = b * L_SZ + c * CH;
    int tid = threadIdx.x;
    int lane = tid & 63, w = tid >> 6;
    int quad = lane >> 4, lm = lane & 15;
    int mh = (w >> 1) * 32, nh = (w & 1) * 64;

    __shared__ float wsc[CH];
    __shared__ u16 XTs[64 * 136];         // [p][t_local], pad 136

    {
        size_t abase = ((size_t)((b * NH + h) * NCK + c)) * CH;
        float a255 = acs_g[abase + 255];
        float at = acs_g[abase + tid];
        wsc[tid] = dtbT[(size_t)h * MROWS + row0 + tid] * expf(a255 - at);
    }
    f32x4 acc[2][4] = {};
    for (int k0 = 0; k0 < CH; k0 += 128) {
        __syncthreads();
        {   // stage scaled-transposed X chunk: thread -> (t row, 32 p)
            int tl = tid >> 1;            // 0..127
            int pseg = (tid & 1) * 32;
            float wv = wsc[k0 + tl];
            const u16* xr = xbc + (size_t)(row0 + k0 + tl) * CDIM + h * HD + pseg;
            for (int q4 = 0; q4 < 4; q4++) {
                bf16x8 v = *(const bf16x8*)(xr + q4 * 8);
                for (int e = 0; e < 8; e++)
                    XTs[(pseg + q4 * 8 + e) * 136 + tl] = f2bf(bf2f((u16)v[e]) * wv);
            }
        }
        __syncthreads();
        for (int ks = 0; ks < 4; ks++) {
            bf16x8 af[2];
            for (int i = 0; i < 2; i++)
                af[i] = *(const bf16x8*)(XTs + (mh + i * 16 + lm) * 136 + ks * 32 + quad * 8);
            for (int j = 0; j < 4; j++) {
                const u16* brow = BmT + (size_t)(nh + j * 16 + lm) * MROWS + row0 + k0 + ks * 32 + quad * 8;
                bf16x8 bfr = *(const bf16x8*)brow;
                for (int i = 0; i < 2; i++)
                    acc[i][j] = __builtin_amdgcn_mfma_f32_16x16x32_bf16(af[i], bfr, acc[i][j], 0, 0, 0);
            }
        }
    }
    float* st = states + (size_t)bid * (HD * DS);
    for (int i = 0; i < 2; i++)
        for (int j = 0; j < 4; j++)
            for (int r = 0; r < 4; r++) {
                int p = mh + i * 16 + quad * 4 + r;
                int n = nh + j * 16 + lm;
                st[p * DS + n] = acc[i][j][r];
            }
}

// ---- 6: inter-chunk scan IN PLACE ----
__global__ void cscan_kernel(float* __restrict__ states, const float* __restrict__ acs_g) {
    int bid = blockIdx.x;
    int h = bid & 63, b = bid >> 6;
    int tid = threadIdx.x;
    float4 carry[8];
    for (int i = 0; i < 8; i++) carry[i] = make_float4(0.f, 0.f, 0.f, 0.f);
    for (int c = 0; c < NCK; c++) {
        size_t base = ((size_t)((b * NCK + c) * NH + h)) * (HD * DS);
        float g = expf(acs_g[((size_t)((b * NH + h) * NCK + c)) * CH + (CH - 1)]);
        float4* sp = (float4*)(states + base);
        for (int i = 0; i < 8; i++) {
            int idx = tid + 256 * i;
            float4 s = sp[idx];
            sp[idx] = carry[i];
            carry[i].x = carry[i].x * g + s.x;
            carry[i].y = carry[i].y * g + s.y;
            carry[i].z = carry[i].z * g + s.z;
            carry[i].w = carry[i].w * g + s.w;
        }
    }
}

// ---- 7: y = Yo + Yd + D_skip*x per (b,c,h) — MFMA, register-built Yd A-frags ----
__global__ __launch_bounds__(256) void y_kernel(const u16* __restrict__ xbc, const float* __restrict__ dtbT,
                                                const float* __restrict__ acs_g, const u16* __restrict__ Gb,
                                                const float* __restrict__ init_st, const float* __restrict__ D_skip,
                                                u16* __restrict__ y) {
    int bid = blockIdx.x;                 // (b,c,h)
    int h = bid & 63, c = (bid >> 6) & 7, b = bid >> 9;
    int bc = b * NCK + c;
    int row0 = b * L_SZ + c * CH;
    int tid = threadIdx.x;
    int lane = tid & 63, w = tid >> 6;
    int wt = w * 64;
    int quad = lane >> 4, lm = lane & 15;

    __shared__ float acs[CH];             // 1 KB
    __shared__ u16 Ssb[64 * 136];         // 17.4 KB  states bf16 [p][n] pad 136
    __shared__ u16 XT[64 * 72];           // 9.2 KB   Xdt^T [p][s_local] pad 72

    acs[tid] = acs_g[((size_t)((b * NH + h) * NCK + c)) * CH + tid];
    {   // init_st f32 [p][n] -> bf16 LDS padded
        const float4* sg = (const float4*)(init_st + ((size_t)(bc * NH + h)) * (HD * DS));
        for (int i = 0; i < 8; i++) {
            int g = tid + 256 * i;
            int p = g >> 5, n4 = (g & 31) * 4;
            float4 v = sg[g];
            ushort4 o;
            o.x = f2bf(v.x); o.y = f2bf(v.y); o.z = f2bf(v.z); o.w = f2bf(v.w);
            *(ushort4*)(Ssb + p * 136 + n4) = o;
        }
    }
    __syncthreads();

    f32x4 acc[4][4] = {};
    // ---- Yo: A = raw Cm rows from global; B = Ssb ----
    for (int i = 0; i < 4; i++) {
        const u16* arow = xbc + (size_t)(row0 + wt + i * 16 + lm) * CDIM + (DI + DS);
        for (int ks = 0; ks < 4; ks++) {
            bf16x8 af = *(const bf16x8*)(arow + ks * 32 + quad * 8);
            for (int j = 0; j < 4; j++) {
                bf16x8 bfr = *(const bf16x8*)(Ssb + (j * 16 + lm) * 136 + ks * 32 + quad * 8);
                acc[i][j] = __builtin_amdgcn_mfma_f32_16x16x32_bf16(af, bfr, acc[i][j], 0, 0, 0);
            }
        }
    }
    for (int i = 0; i < 4; i++) {
        float et[4];
        for (int r = 0; r < 4; r++) et[r] = expf(acs[wt + i * 16 + quad * 4 + r]);
        for (int j = 0; j < 4; j++)
            for (int r = 0; r < 4; r++) acc[i][j][r] *= et[r];
    }

    // ---- Yd: A-frag built in registers from masked Gb + exp; B = XT (dt folded) ----
    const u16* gball = Gb + (size_t)bc * CH * CH;
    for (int s0 = 0; s0 < CH; s0 += 64) {
        __syncthreads();
        {   // XT[p][s_local] = x[s][p] * dt[s]
            int r = tid >> 2, cseg = (tid & 3) * 16;
            int row = row0 + s0 + r;
            float dv = dtbT[(size_t)h * MROWS + row];
            const u16* xr = xbc + (size_t)row * CDIM + h * HD + cseg;
            for (int q8 = 0; q8 < 2; q8++) {
                bf16x8 v = *(const bf16x8*)(xr + q8 * 8);
                for (int e = 0; e < 8; e++)
                    XT[(cseg + q8 * 8 + e) * 72 + r] = f2bf(bf2f((u16)v[e]) * dv);
            }
        }
        __syncthreads();
        if (wt + 63 < s0) continue;
        for (int i = 0; i < 4; i++) {
            int tTop = wt + i * 16 + 15;
            if (tTop < s0) continue;
            int t = wt + i * 16 + lm;
            float at = acs[t];
            const u16* grow_ = gball + (size_t)t * CH + s0;
            for (int ks = 0; ks < 2; ks++) {
                if (s0 + ks * 32 > tTop) continue;
                bf16x8 g8 = *(const bf16x8*)(grow_ + ks * 32 + quad * 8);
                const float* asp = &acs[s0 + ks * 32 + quad * 8];
                bf16x8 af;
                for (int e = 0; e < 8; e++) {
                    float m = bf2f((u16)g8[e]) * expf(fminf(at - asp[e], 0.f));
                    af[e] = (short)f2bf(m);
                }
                for (int j = 0; j < 4; j++) {
                    bf16x8 bfr = *(const bf16x8*)(XT + (j * 16 + lm) * 72 + ks * 32 + quad * 8);
                    acc[i][j] = __builtin_amdgcn_mfma_f32_16x16x32_bf16(af, bfr, acc[i][j], 0, 0, 0);
                }
            }
        }
    }

    // ---- epilogue ----
    float dsk = D_skip[h];
    for (int i = 0; i < 4; i++)
        for (int r = 0; r < 4; r++) {
            int grow = row0 + wt + i * 16 + quad * 4 + r;
            const u16* xrow = xbc + (size_t)grow * CDIM + h * HD;
            u16* yrow = y + (size_t)grow * DI + h * HD;
            for (int j = 0; j < 4; j++) {
                int p = j * 16 + lm;
                yrow[p] = f2bf(acc[i][j][r] + dsk * bf2f(xrow[p]));
            }
        }
}

// ---- 8: out = (y * silu(z)) * rsqrt(mean(yg^2)+eps) * norm_w — vectorized ----
__global__ void final_kernel(const u16* __restrict__ y, const u16* __restrict__ zx,
                             const float* __restrict__ norm_w, float* __restrict__ out) {
    int row = blockIdx.x;
    int tid = threadIdx.x;
    int col0 = tid * 16;
    __shared__ float red[4];
    float yg[16];
    float ss = 0.f;
    {
        bf16x8 zv0 = *(const bf16x8*)(zx + (size_t)row * NP + col0);
        bf16x8 zv1 = *(const bf16x8*)(zx + (size_t)row * NP + col0 + 8);
        bf16x8 yv0 = *(const bf16x8*)(y  + (size_t)row * DI + col0);
        bf16x8 yv1 = *(const bf16x8*)(y  + (size_t)row * DI + col0 + 8);
        for (int e = 0; e < 8; e++) {
            float z = bf2f((u16)zv0[e]);
            float g = bf2f((u16)yv0[e]) * (z / (1.f + expf(-z)));
            yg[e] = g; ss += g * g;
        }
        for (int e = 0; e < 8; e++) {
            float z = bf2f((u16)zv1[e]);
            float g = bf2f((u16)yv1[e]) * (z / (1.f + expf(-z)));
            yg[8 + e] = g; ss += g * g;
        }
    }
    for (int off = 32; off; off >>= 1) ss += __shfl_down(ss, off);
    if ((tid & 63) == 0) red[tid >> 6] = ss;
    __syncthreads();
    if (tid == 0) red[0] = red[0] + red[1] + red[2] + red[3];
    __syncthreads();
    float inv = rsqrtf(red[0] / (float)DI + 1e-5f);
    for (int q = 0; q < 4; q++) {
        float4 nw = *(const float4*)(norm_w + col0 + q * 4);
        float4 o;
        o.x = yg[q * 4 + 0] * inv * nw.x;
        o.y = yg[q * 4 + 1] * inv * nw.y;
        o.z = yg[q * 4 + 2] * inv * nw.z;
        o.w = yg[q * 4 + 3] * inv * nw.w;
        *(float4*)(out + (size_t)row * DI + col0 + q * 4) = o;
    }
}

extern "C" void kernel_launch(void* const* d_in, const int* in_sizes, int n_in,
                              void* d_out, int out_size, void* d_ws, size_t ws_size,
                              hipStream_t stream) {
    const float* u       = (const float*)d_in[0];
    const float* w_in    = (const float*)d_in[1];
    const float* conv_w  = (const float*)d_in[2];
    const float* conv_b  = (const float*)d_in[3];
    const float* dt_bias = (const float*)d_in[4];
    const float* A_log   = (const float*)d_in[5];
    const float* D_skip  = (const float*)d_in[6];
    const float* norm_w  = (const float*)d_in[7];
    float* out = (float*)d_out;

    const size_t NEEDED = 179306496ull;   // layout unchanged
    if (ws_size < NEEDED) return;

    char* ws = (char*)d_ws;
    const size_t R = 70254592ull;
    u16*   zx   = (u16*)ws;                         // 70,254,592
    u16*   ubf  = (u16*)(ws + R);                   // GEMM phase
    u16*   wtb  = (u16*)(ws + R + 16777216);        // GEMM phase
    u16*   xbc  = (u16*)(ws + R);                   // post-GEMM, 35,651,584
    float* dtbT = (float*)(ws + R + 35651584);      // 1 MB  [h][row]
    float* acs  = (float*)(ws + R + 36700160);      // 1 MB
    u16*   Gb   = (u16*)(ws + R + 37748736);        // 2 MB  masked bf16
    u16*   BmT  = (u16*)(ws + R + 39845888);        // 1 MB  [n][row]
    float* stat = (float*)(ws + R + 41943040);      // 33.5 MB
    u16*   yb   = (u16*)(ws + R + 75497472);        // 33.5 MB

    cvt_u_kernel<<<8192, 256, 0, stream>>>(u, ubf);
    transpose_w_kernel<<<dim3(268, 64), 256, 0, stream>>>(w_in, wtb);
    gemm_kernel<<<GEMM_NM * GEMM_NN, 256, 0, stream>>>(ubf, wtb, zx);
    conv_silu_kernel<<<dim3(17, 256), 512, 0, stream>>>(zx, conv_w, conv_b, xbc);
    dt_scan_kernel<<<1024, 256, 0, stream>>>(zx, dt_bias, A_log, dtbT, acs);
    g_kernel<<<256, 256, 0, stream>>>(xbc, Gb);
    bmt_kernel<<<dim3(2, 64), 256, 0, stream>>>(xbc, BmT);
    states_kernel<<<1024, 256, 0, stream>>>(xbc, BmT, dtbT, acs, stat);
    cscan_kernel<<<128, 256, 0, stream>>>(stat, acs);
    y_kernel<<<1024, 256, 0, stream>>>(xbc, dtbT, acs, Gb, stat, D_skip, yb);
    final_kernel<<<4096, 256, 0, stream>>>(yb, zx, norm_w, out);
}

// Round 7
// 528.282 us; speedup vs baseline: 1.2064x; 1.0086x over previous
//
#include <hip/hip_runtime.h>
#include <hip/hip_bf16.h>

// ---- problem constants ----
#define B_SZ   2
#define L_SZ   2048
#define DM     2048
#define DS     128
#define DCV    4
#define HD     64
#define CH     256
#define DI     4096
#define NH     64
#define DIP    8512
#define CDIM   4352
#define NP     8576      // DIP padded to 67*128
#define MROWS  4096      // B_SZ*L_SZ
#define NCK    8         // L_SZ/CH

typedef __attribute__((ext_vector_type(8))) short bf16x8;
typedef __attribute__((ext_vector_type(4))) float f32x4;
typedef unsigned short u16;

__device__ __forceinline__ u16 f2bf(float f) {
    union { float f; unsigned u; } c; c.f = f;
    unsigned r = c.u + 0x7fffu + ((c.u >> 16) & 1u);
    return (u16)(r >> 16);
}
__device__ __forceinline__ float bf2f(u16 b) {
    union { unsigned u; float f; } c; c.u = ((unsigned)b) << 16; return c.f;
}

// async global->LDS copy, 16 B per lane (global_load_lds_dwordx4)
__device__ __forceinline__ void async16(const u16* g, u16* l) {
    __builtin_amdgcn_global_load_lds(
        (const __attribute__((address_space(1))) unsigned int*)(g),
        (__attribute__((address_space(3))) unsigned int*)(l),
        16, 0, 0);
}

// ---- 0a: u f32 -> bf16 ----
__global__ void cvt_u_kernel(const float* __restrict__ u, u16* __restrict__ ub) {
    int i = blockIdx.x * 256 + threadIdx.x;
    float4 v = ((const float4*)u)[i];
    ushort4 o;
    o.x = f2bf(v.x); o.y = f2bf(v.y); o.z = f2bf(v.z); o.w = f2bf(v.w);
    ((ushort4*)ub)[i] = o;
}

// ---- 0b: w_in (K=2048 x DIP) f32 -> w_inT (NP x K) bf16, zero-pad rows >= DIP ----
__global__ void transpose_w_kernel(const float* __restrict__ w, u16* __restrict__ wt) {
    __shared__ float tile[32][33];
    int n0 = blockIdx.x * 32, k0 = blockIdx.y * 32;
    int tx = threadIdx.x & 31, ty = threadIdx.x >> 5;
    for (int j = 0; j < 32; j += 8) {
        int k = k0 + ty + j, n = n0 + tx;
        tile[ty + j][tx] = (n < DIP) ? w[(size_t)k * DIP + n] : 0.f;
    }
    __syncthreads();
    for (int j = 0; j < 32; j += 8) {
        int n = n0 + ty + j, k = k0 + tx;
        wt[(size_t)n * DM + k] = f2bf(tile[tx][ty + j]);
    }
}

// ---- 1: GEMM zxbcdt = u @ w_in -> bf16 [MROWS][NP] ----
// Round-4 proven kernel: 128^2 tile, m97 structure, grouped-M, XOR swizzle,
// XCD-aware bid swizzle. Measured: 171 us, MfmaUtil 38.7%, FETCH 154MB,
// WRITE 68.6MB, 0 bank conflicts. The 256^2/BK32 line is CLOSED (3 failures).
#define GEMM_NM 32
#define GEMM_NN 67
#define GEMM_GM 8
__global__ __launch_bounds__(256) void gemm_kernel(const u16* __restrict__ A,
                                                   const u16* __restrict__ Bt,
                                                   u16* __restrict__ C) {
    __shared__ u16 As[128 * 64];
    __shared__ u16 Bs[128 * 64];
    const int bid0 = blockIdx.x;
    const int bid = (bid0 & 7) * ((GEMM_NM * GEMM_NN) / 8) + (bid0 >> 3);  // XCD swizzle
    const int width = GEMM_GM * GEMM_NN;
    const int group = bid / width;
    const int rem = bid - group * width;
    const int pid_m = group * GEMM_GM + (rem % GEMM_GM);
    const int pid_n = rem / GEMM_GM;
    const int m0 = pid_m * 128, n0 = pid_n * 128;

    const int tid = threadIdx.x;
    const int lane = tid & 63, w = tid >> 6;
    const int wm = (w >> 1) * 64, wn = (w & 1) * 64;
    const int quad = lane >> 4, lm = lane & 15;
    const int lr = lane >> 3;
    const int pc = lane & 7;
    const int lcl = ((pc ^ lr) * 8);
    const int sx = (lm & 7);
    f32x4 acc[4][4] = {};
    for (int k0 = 0; k0 < DM; k0 += 64) {
        __syncthreads();
        for (int j = 0; j < 4; j++) {
            int row = w * 32 + j * 8 + lr;
            async16(A  + (size_t)(m0 + row) * DM + k0 + lcl, As + row * 64 + pc * 8);
            async16(Bt + (size_t)(n0 + row) * DM + k0 + lcl, Bs + row * 64 + pc * 8);
        }
        __syncthreads();
        for (int half = 0; half < 2; half++) {
            int cq = half * 4 + quad;
            int co = (cq ^ sx) * 8;
            bf16x8 af[4], bfr[4];
            for (int i = 0; i < 4; i++) af[i]  = *(const bf16x8*)(As + (wm + i * 16 + lm) * 64 + co);
            for (int j = 0; j < 4; j++) bfr[j] = *(const bf16x8*)(Bs + (wn + j * 16 + lm) * 64 + co);
            for (int i = 0; i < 4; i++)
                for (int j = 0; j < 4; j++)
                    acc[i][j] = __builtin_amdgcn_mfma_f32_16x16x32_bf16(af[i], bfr[j], acc[i][j], 0, 0, 0);
        }
    }
    for (int i = 0; i < 4; i++)
        for (int j = 0; j < 4; j++)
            for (int r = 0; r < 4; r++) {
                int gm = m0 + wm + i * 16 + quad * 4 + r;
                int gn = n0 + wn + j * 16 + lm;
                C[(size_t)gm * NP + gn] = f2bf(acc[i][j][r]);
            }
}

// ---- 2: causal depthwise conv(4) + SiLU — vectorized, 8 channels/thread ----
__global__ void conv_silu_kernel(const u16* __restrict__ zx, const float* __restrict__ cw,
                                 const float* __restrict__ cb, u16* __restrict__ xbc) {
    int tid = threadIdx.x;
    int c8  = blockIdx.x * 32 + (tid & 31);        // 0..543
    int row = blockIdx.y * 16 + (tid >> 5);        // 0..4095
    int c0  = c8 * 8;
    int l = row & (L_SZ - 1);

    float w_[8][4];
    {
        const float4* wp = (const float4*)(cw + (size_t)c0 * 4);
        for (int e = 0; e < 8; e++) {
            float4 v = wp[e];
            w_[e][0] = v.x; w_[e][1] = v.y; w_[e][2] = v.z; w_[e][3] = v.w;
        }
    }
    float acc[8];
    {
        float4 b0 = *(const float4*)(cb + c0);
        float4 b1 = *(const float4*)(cb + c0 + 4);
        acc[0] = b0.x; acc[1] = b0.y; acc[2] = b0.z; acc[3] = b0.w;
        acc[4] = b1.x; acc[5] = b1.y; acc[6] = b1.z; acc[7] = b1.w;
    }
    for (int k = 0; k < DCV; k++) {
        int ls = l - 3 + k;
        if (ls >= 0) {
            bf16x8 v = *(const bf16x8*)(zx + (size_t)(row - 3 + k) * NP + DI + c0);
            for (int e = 0; e < 8; e++)
                acc[e] += bf2f((u16)v[e]) * w_[e][k];
        }
    }
    bf16x8 o;
    for (int e = 0; e < 8; e++) {
        float s = acc[e] / (1.f + expf(-acc[e]));
        o[e] = (short)f2bf(s);
    }
    *(bf16x8*)(xbc + (size_t)row * CDIM + c0) = o;
}

// ---- 3: dt = softplus(raw+bias) -> dtbT[h][row]; per-chunk cumsum of dA -> acs ----
__global__ void dt_scan_kernel(const u16* __restrict__ zx, const float* __restrict__ dt_bias,
                               const float* __restrict__ A_log, float* __restrict__ dtbT,
                               float* __restrict__ acs) {
    int bid = blockIdx.x;
    int h = bid & 63, c = (bid >> 6) & 7, b = bid >> 9;
    int t = threadIdx.x;
    int row = b * L_SZ + c * CH + t;
    float raw = bf2f(zx[(size_t)row * NP + (DI + CDIM) + h]) + dt_bias[h];
    float dtv = (raw > 20.f) ? raw : log1pf(expf(raw));
    float dA = dtv * (-expf(A_log[h]));
    dtbT[(size_t)h * MROWS + row] = dtv;
    __shared__ float sc[256];
    sc[t] = dA;
    for (int off = 1; off < 256; off <<= 1) {
        __syncthreads();
        float v = (t >= off) ? sc[t - off] : 0.f;
        __syncthreads();
        sc[t] += v;
    }
    acs[((size_t)((b * NH + h) * NCK + c)) * CH + t] = sc[t];
}

// ---- 4: Gb[t][s] = masked bf16( sum_n Cm[t,n]*Bm[s,n] ) per (b,c) ----
__global__ void g_kernel(const u16* __restrict__ xbc, u16* __restrict__ Gb) {
    int blk = blockIdx.x;
    int bc = blk >> 4;
    int tile = blk & 15;
    int tb0 = (tile >> 2) * 64, sb0 = (tile & 3) * 64;
    int row0 = bc * CH;
    __shared__ float Ct[64][65], Bt_[64][65];
    int tq = (threadIdx.x >> 4) * 4;
    int sq = (threadIdx.x & 15) * 4;
    float acc[4][4] = {};
    for (int nh = 0; nh < 2; nh++) {
        __syncthreads();
        int r = threadIdx.x >> 2, cc = (threadIdx.x & 3) * 16;
        for (int q = 0; q < 16; q += 4) {
            ushort4 cv = *(const ushort4*)&xbc[(size_t)(row0 + tb0 + r) * CDIM + (DI + DS) + nh * 64 + cc + q];
            ushort4 bv = *(const ushort4*)&xbc[(size_t)(row0 + sb0 + r) * CDIM + DI + nh * 64 + cc + q];
            Ct[r][cc + q] = bf2f(cv.x); Ct[r][cc + q + 1] = bf2f(cv.y); Ct[r][cc + q + 2] = bf2f(cv.z); Ct[r][cc + q + 3] = bf2f(cv.w);
            Bt_[r][cc + q] = bf2f(bv.x); Bt_[r][cc + q + 1] = bf2f(bv.y); Bt_[r][cc + q + 2] = bf2f(bv.z); Bt_[r][cc + q + 3] = bf2f(bv.w);
        }
        __syncthreads();
        for (int n = 0; n < 64; n++) {
            float a[4], bb[4];
            for (int i = 0; i < 4; i++) a[i] = Ct[tq + i][n];
            for (int j = 0; j < 4; j++) bb[j] = Bt_[sq + j][n];
            for (int i = 0; i < 4; i++)
                for (int j = 0; j < 4; j++) acc[i][j] += a[i] * bb[j];
        }
    }
    for (int i = 0; i < 4; i++)
        for (int j = 0; j < 4; j++) {
            int t = tb0 + tq + i, s = sb0 + sq + j;
            Gb[((size_t)(bc * CH + t)) * CH + s] = (s <= t) ? f2bf(acc[i][j]) : (u16)0;
        }
}

// ---- 4b: BmT[n][row] = xbc[row][DI+n]  (128 x 4096 bf16) ----
__global__ void bmt_kernel(const u16* __restrict__ xbc, u16* __restrict__ BmT) {
    __shared__ u16 tile[64 * 72];
    int n0 = blockIdx.x * 64, r0 = blockIdx.y * 64;
    int tid = threadIdx.x;
    {
        int r = tid >> 2, seg = (tid & 3) * 16;
        const u16* src = xbc + (size_t)(r0 + r) * CDIM + DI + n0 + seg;
        *(int4*)(tile + r * 72 + seg)     = *(const int4*)(src);
        *(int4*)(tile + r * 72 + seg + 8) = *(const int4*)(src + 8);
    }
    __syncthreads();
    {
        int n = tid >> 2, seg = (tid & 3) * 16;
        union { u16 v[16]; int4 q[2]; } o;
        for (int q = 0; q < 16; q++) o.v[q] = tile[(seg + q) * 72 + n];
        u16* dst = BmT + (size_t)(n0 + n) * MROWS + r0 + seg;
        *(int4*)(dst)     = o.q[0];
        *(int4*)(dst + 8) = o.q[1];
    }
}

// ---- 5: states[p][n] = sum_t (X[t,p]*dt[t]*decay[t]) * Bm[t,n]  per (b,c,h) — MFMA ----
__global__ __launch_bounds__(256) void states_kernel(const u16* __restrict__ xbc, const u16* __restrict__ BmT,
                                                     const float* __restrict__ dtbT, const float* __restrict__ acs_g,
                                                     float* __restrict__ states) {
    int bid = blockIdx.x;                 // (b,c,h)
    int h = bid & 63, c = (bid >> 6) & 7, b = bid >> 9;
    int row0 = b * L_SZ + c * CH;
    int tid = threadIdx.x;
    int lane = tid & 63, w = tid >> 6;
    int quad = lane >> 4, lm = lane & 15;
    int mh = (w >> 1) * 32, nh = (w & 1) * 64;

    __shared__ float wsc[CH];
    __shared__ u16 XTs[64 * 136];         // [p][t_local], pad 136

    {
        size_t abase = ((size_t)((b * NH + h) * NCK + c)) * CH;
        float a255 = acs_g[abase + 255];
        float at = acs_g[abase + tid];
        wsc[tid] = dtbT[(size_t)h * MROWS + row0 + tid] * expf(a255 - at);
    }
    f32x4 acc[2][4] = {};
    for (int k0 = 0; k0 < CH; k0 += 128) {
        __syncthreads();
        {   // stage scaled-transposed X chunk: thread -> (t row, 32 p)
            int tl = tid >> 1;            // 0..127
            int pseg = (tid & 1) * 32;
            float wv = wsc[k0 + tl];
            const u16* xr = xbc + (size_t)(row0 + k0 + tl) * CDIM + h * HD + pseg;
            for (int q4 = 0; q4 < 4; q4++) {
                bf16x8 v = *(const bf16x8*)(xr + q4 * 8);
                for (int e = 0; e < 8; e++)
                    XTs[(pseg + q4 * 8 + e) * 136 + tl] = f2bf(bf2f((u16)v[e]) * wv);
            }
        }
        __syncthreads();
        for (int ks = 0; ks < 4; ks++) {
            bf16x8 af[2];
            for (int i = 0; i < 2; i++)
                af[i] = *(const bf16x8*)(XTs + (mh + i * 16 + lm) * 136 + ks * 32 + quad * 8);
            for (int j = 0; j < 4; j++) {
                const u16* brow = BmT + (size_t)(nh + j * 16 + lm) * MROWS + row0 + k0 + ks * 32 + quad * 8;
                bf16x8 bfr = *(const bf16x8*)brow;
                for (int i = 0; i < 2; i++)
                    acc[i][j] = __builtin_amdgcn_mfma_f32_16x16x32_bf16(af[i], bfr, acc[i][j], 0, 0, 0);
            }
        }
    }
    float* st = states + (size_t)bid * (HD * DS);
    for (int i = 0; i < 2; i++)
        for (int j = 0; j < 4; j++)
            for (int r = 0; r < 4; r++) {
                int p = mh + i * 16 + quad * 4 + r;
                int n = nh + j * 16 + lm;
                st[p * DS + n] = acc[i][j][r];
            }
}

// ---- 6: inter-chunk scan IN PLACE — 512 blocks (4x TLP vs 128) ----
// Scan is over c only; (p,n) fully parallel. Each block owns 2 of the 8
// float4-groups => 512 = 2(b) x 64(h) x 4(quarter) blocks, carry[2] each.
// No barriers/LDS — hang-impossible change.
__global__ void cscan_kernel(float* __restrict__ states, const float* __restrict__ acs_g) {
    int bid = blockIdx.x;
    int q = bid & 3;
    int h = (bid >> 2) & 63;
    int b = bid >> 8;
    int tid = threadIdx.x;
    float4 carry[2];
    carry[0] = make_float4(0.f, 0.f, 0.f, 0.f);
    carry[1] = make_float4(0.f, 0.f, 0.f, 0.f);
    for (int c = 0; c < NCK; c++) {
        size_t base = ((size_t)((b * NCK + c) * NH + h)) * (HD * DS);
        float g = expf(acs_g[((size_t)((b * NH + h) * NCK + c)) * CH + (CH - 1)]);
        float4* sp = (float4*)(states + base);
        for (int i = 0; i < 2; i++) {
            int idx = tid + 256 * (q * 2 + i);
            float4 s = sp[idx];
            sp[idx] = carry[i];
            carry[i].x = carry[i].x * g + s.x;
            carry[i].y = carry[i].y * g + s.y;
            carry[i].z = carry[i].z * g + s.z;
            carry[i].w = carry[i].w * g + s.w;
        }
    }
}

// ---- 7: y = Yo + Yd + D_skip*x per (b,c,h) — MFMA, register-built Yd A-frags ----
__global__ __launch_bounds__(256) void y_kernel(const u16* __restrict__ xbc, const float* __restrict__ dtbT,
                                                const float* __restrict__ acs_g, const u16* __restrict__ Gb,
                                                const float* __restrict__ init_st, const float* __restrict__ D_skip,
                                                u16* __restrict__ y) {
    int bid = blockIdx.x;                 // (b,c,h)
    int h = bid & 63, c = (bid >> 6) & 7, b = bid >> 9;
    int bc = b * NCK + c;
    int row0 = b * L_SZ + c * CH;
    int tid = threadIdx.x;
    int lane = tid & 63, w = tid >> 6;
    int wt = w * 64;
    int quad = lane >> 4, lm = lane & 15;

    __shared__ float acs[CH];             // 1 KB
    __shared__ u16 Ssb[64 * 136];         // 17.4 KB  states bf16 [p][n] pad 136
    __shared__ u16 XT[64 * 72];           // 9.2 KB   Xdt^T [p][s_local] pad 72

    acs[tid] = acs_g[((size_t)((b * NH + h) * NCK + c)) * CH + tid];
    {   // init_st f32 [p][n] -> bf16 LDS padded
        const float4* sg = (const float4*)(init_st + ((size_t)(bc * NH + h)) * (HD * DS));
        for (int i = 0; i < 8; i++) {
            int g = tid + 256 * i;
            int p = g >> 5, n4 = (g & 31) * 4;
            float4 v = sg[g];
            ushort4 o;
            o.x = f2bf(v.x); o.y = f2bf(v.y); o.z = f2bf(v.z); o.w = f2bf(v.w);
            *(ushort4*)(Ssb + p * 136 + n4) = o;
        }
    }
    __syncthreads();

    f32x4 acc[4][4] = {};
    // ---- Yo: A = raw Cm rows from global; B = Ssb ----
    for (int i = 0; i < 4; i++) {
        const u16* arow = xbc + (size_t)(row0 + wt + i * 16 + lm) * CDIM + (DI + DS);
        for (int ks = 0; ks < 4; ks++) {
            bf16x8 af = *(const bf16x8*)(arow + ks * 32 + quad * 8);
            for (int j = 0; j < 4; j++) {
                bf16x8 bfr = *(const bf16x8*)(Ssb + (j * 16 + lm) * 136 + ks * 32 + quad * 8);
                acc[i][j] = __builtin_amdgcn_mfma_f32_16x16x32_bf16(af, bfr, acc[i][j], 0, 0, 0);
            }
        }
    }
    for (int i = 0; i < 4; i++) {
        float et[4];
        for (int r = 0; r < 4; r++) et[r] = expf(acs[wt + i * 16 + quad * 4 + r]);
        for (int j = 0; j < 4; j++)
            for (int r = 0; r < 4; r++) acc[i][j][r] *= et[r];
    }

    // ---- Yd: A-frag built in registers from masked Gb + exp; B = XT (dt folded) ----
    const u16* gball = Gb + (size_t)bc * CH * CH;
    for (int s0 = 0; s0 < CH; s0 += 64) {
        __syncthreads();
        {   // XT[p][s_local] = x[s][p] * dt[s]
            int r = tid >> 2, cseg = (tid & 3) * 16;
            int row = row0 + s0 + r;
            float dv = dtbT[(size_t)h * MROWS + row];
            const u16* xr = xbc + (size_t)row * CDIM + h * HD + cseg;
            for (int q8 = 0; q8 < 2; q8++) {
                bf16x8 v = *(const bf16x8*)(xr + q8 * 8);
                for (int e = 0; e < 8; e++)
                    XT[(cseg + q8 * 8 + e) * 72 + r] = f2bf(bf2f((u16)v[e]) * dv);
            }
        }
        __syncthreads();
        if (wt + 63 < s0) continue;
        for (int i = 0; i < 4; i++) {
            int tTop = wt + i * 16 + 15;
            if (tTop < s0) continue;
            int t = wt + i * 16 + lm;
            float at = acs[t];
            const u16* grow_ = gball + (size_t)t * CH + s0;
            for (int ks = 0; ks < 2; ks++) {
                if (s0 + ks * 32 > tTop) continue;
                bf16x8 g8 = *(const bf16x8*)(grow_ + ks * 32 + quad * 8);
                const float* asp = &acs[s0 + ks * 32 + quad * 8];
                bf16x8 af;
                for (int e = 0; e < 8; e++) {
                    float m = bf2f((u16)g8[e]) * expf(fminf(at - asp[e], 0.f));
                    af[e] = (short)f2bf(m);
                }
                for (int j = 0; j < 4; j++) {
                    bf16x8 bfr = *(const bf16x8*)(XT + (j * 16 + lm) * 72 + ks * 32 + quad * 8);
                    acc[i][j] = __builtin_amdgcn_mfma_f32_16x16x32_bf16(af, bfr, acc[i][j], 0, 0, 0);
                }
            }
        }
    }

    // ---- epilogue ----
    float dsk = D_skip[h];
    for (int i = 0; i < 4; i++)
        for (int r = 0; r < 4; r++) {
            int grow = row0 + wt + i * 16 + quad * 4 + r;
            const u16* xrow = xbc + (size_t)grow * CDIM + h * HD;
            u16* yrow = y + (size_t)grow * DI + h * HD;
            for (int j = 0; j < 4; j++) {
                int p = j * 16 + lm;
                yrow[p] = f2bf(acc[i][j][r] + dsk * bf2f(xrow[p]));
            }
        }
}

// ---- 8: out = (y * silu(z)) * rsqrt(mean(yg^2)+eps) * norm_w — vectorized ----
__global__ void final_kernel(const u16* __restrict__ y, const u16* __restrict__ zx,
                             const float* __restrict__ norm_w, float* __restrict__ out) {
    int row = blockIdx.x;
    int tid = threadIdx.x;
    int col0 = tid * 16;
    __shared__ float red[4];
    float yg[16];
    float ss = 0.f;
    {
        bf16x8 zv0 = *(const bf16x8*)(zx + (size_t)row * NP + col0);
        bf16x8 zv1 = *(const bf16x8*)(zx + (size_t)row * NP + col0 + 8);
        bf16x8 yv0 = *(const bf16x8*)(y  + (size_t)row * DI + col0);
        bf16x8 yv1 = *(const bf16x8*)(y  + (size_t)row * DI + col0 + 8);
        for (int e = 0; e < 8; e++) {
            float z = bf2f((u16)zv0[e]);
            float g = bf2f((u16)yv0[e]) * (z / (1.f + expf(-z)));
            yg[e] = g; ss += g * g;
        }
        for (int e = 0; e < 8; e++) {
            float z = bf2f((u16)zv1[e]);
            float g = bf2f((u16)yv1[e]) * (z / (1.f + expf(-z)));
            yg[8 + e] = g; ss += g * g;
        }
    }
    for (int off = 32; off; off >>= 1) ss += __shfl_down(ss, off);
    if ((tid & 63) == 0) red[tid >> 6] = ss;
    __syncthreads();
    if (tid == 0) red[0] = red[0] + red[1] + red[2] + red[3];
    __syncthreads();
    float inv = rsqrtf(red[0] / (float)DI + 1e-5f);
    for (int q = 0; q < 4; q++) {
        float4 nw = *(const float4*)(norm_w + col0 + q * 4);
        float4 o;
        o.x = yg[q * 4 + 0] * inv * nw.x;
        o.y = yg[q * 4 + 1] * inv * nw.y;
        o.z = yg[q * 4 + 2] * inv * nw.z;
        o.w = yg[q * 4 + 3] * inv * nw.w;
        *(float4*)(out + (size_t)row * DI + col0 + q * 4) = o;
    }
}

extern "C" void kernel_launch(void* const* d_in, const int* in_sizes, int n_in,
                              void* d_out, int out_size, void* d_ws, size_t ws_size,
                              hipStream_t stream) {
    const float* u       = (const float*)d_in[0];
    const float* w_in    = (const float*)d_in[1];
    const float* conv_w  = (const float*)d_in[2];
    const float* conv_b  = (const float*)d_in[3];
    const float* dt_bias = (const float*)d_in[4];
    const float* A_log   = (const float*)d_in[5];
    const float* D_skip  = (const float*)d_in[6];
    const float* norm_w  = (const float*)d_in[7];
    float* out = (float*)d_out;

    const size_t NEEDED = 179306496ull;   // layout unchanged
    if (ws_size < NEEDED) return;

    char* ws = (char*)d_ws;
    const size_t R = 70254592ull;
    u16*   zx   = (u16*)ws;                         // 70,254,592
    u16*   ubf  = (u16*)(ws + R);                   // GEMM phase
    u16*   wtb  = (u16*)(ws + R + 16777216);        // GEMM phase
    u16*   xbc  = (u16*)(ws + R);                   // post-GEMM, 35,651,584
    float* dtbT = (float*)(ws + R + 35651584);      // 1 MB  [h][row]
    float* acs  = (float*)(ws + R + 36700160);      // 1 MB
    u16*   Gb   = (u16*)(ws + R + 37748736);        // 2 MB  masked bf16
    u16*   BmT  = (u16*)(ws + R + 39845888);        // 1 MB  [n][row]
    float* stat = (float*)(ws + R + 41943040);      // 33.5 MB
    u16*   yb   = (u16*)(ws + R + 75497472);        // 33.5 MB

    cvt_u_kernel<<<8192, 256, 0, stream>>>(u, ubf);
    transpose_w_kernel<<<dim3(268, 64), 256, 0, stream>>>(w_in, wtb);
    gemm_kernel<<<GEMM_NM * GEMM_NN, 256, 0, stream>>>(ubf, wtb, zx);
    conv_silu_kernel<<<dim3(17, 256), 512, 0, stream>>>(zx, conv_w, conv_b, xbc);
    dt_scan_kernel<<<1024, 256, 0, stream>>>(zx, dt_bias, A_log, dtbT, acs);
    g_kernel<<<256, 256, 0, stream>>>(xbc, Gb);
    bmt_kernel<<<dim3(2, 64), 256, 0, stream>>>(xbc, BmT);
    states_kernel<<<1024, 256, 0, stream>>>(xbc, BmT, dtbT, acs, stat);
    cscan_kernel<<<512, 256, 0, stream>>>(stat, acs);
    y_kernel<<<1024, 256, 0, stream>>>(xbc, dtbT, acs, Gb, stat, D_skip, yb);
    final_kernel<<<4096, 256, 0, stream>>>(yb, zx, norm_w, out);
}